// Round 7
// baseline (316.375 us; speedup 1.0000x reference)
//
#include <hip/hip_runtime.h>
#include <hip/hip_bf16.h>
#include <hip/hip_fp16.h>
#include <math.h>

// Problem constants (fixed by setup_inputs)
#define D_MODEL   256
#define D_FFN     1024
#define N_LEVELS  4
#define N_HEADS   8
#define N_POINTS  4
#define BATCH     2
#define LQ        8192
#define S_TOTAL   21760            // 128*128 + 64*64 + 32*32 + 16*16
#define M_Q       (BATCH*LQ)       // 16384
#define M_V       (BATCH*S_TOTAL)  // 43520
#define VT64      (M_V/64)         // 680 row tiles for value GEMM

typedef __attribute__((ext_vector_type(8))) short bf16x8;   // 8 bf16 = 4 VGPRs
typedef __attribute__((ext_vector_type(4))) float floatx4;  // mfma C/D

struct alignas(8)  bh4 { __hip_bfloat16 a, b, c, d; };
struct alignas(16) bh8 { __hip_bfloat16 v[8]; };

__device__ __forceinline__ void gld_lds16(const void* g, void* l) {
    __builtin_amdgcn_global_load_lds(
        (const __attribute__((address_space(1))) void*)g,
        (__attribute__((address_space(3))) void*)l, 16, 0, 0);
}

__device__ __forceinline__ bh4 pack4(float4 a) {
    return { __float2bfloat16(a.x), __float2bfloat16(a.y),
             __float2bfloat16(a.z), __float2bfloat16(a.w) };
}

// ---------------------------------------------------------------------------
// 64x64 bf16 MFMA core (R3 version: triple-buffer, distance-2 counted vmcnt).
// Neutral vs dbuf in R3 but kept (measured 294.75 us with it).
// ---------------------------------------------------------------------------
template<int K>
__device__ __forceinline__ void gemm_core64(const __hip_bfloat16* __restrict__ A,
                                            const __hip_bfloat16* __restrict__ Bt,
                                            int row0, int nb0, int lda, int ldb,
                                            short* As, short* Bs, floatx4 (&acc)[4])
{
    constexpr int NIT = K / 32;
    static_assert(NIT >= 2, "");
    const int tid  = threadIdx.x;
    const int w    = tid >> 6;
    const int lane = tid & 63;
    const int quad = lane >> 4;
    const int l15  = lane & 15;
    const size_t ldaB = (size_t)lda * 2, ldbB = (size_t)ldb * 2;

    const int o = w * 1024 + lane * 16;          // byte offset in 4KB tile
    const char* gA = (const char*)A + (size_t)(row0 + (o >> 6)) * ldaB + (o & 63);
    const char* gB = (const char*)Bt + (size_t)(nb0 + (o >> 6)) * ldbB + (o & 63);
    const int lofs = w * 512;                    // shorts

    gld_lds16(gA,      As + lofs);
    gld_lds16(gB,      Bs + lofs);
    gld_lds16(gA + 64, As + 2048 + lofs);
    gld_lds16(gB + 64, Bs + 2048 + lofs);

    int oc = 0, on = 2048, of = 4096;            // cur / next / far buffer offsets
#pragma unroll
    for (int it = 0; it < NIT; ++it) {
        if (it + 1 < NIT) asm volatile("s_waitcnt vmcnt(2)" ::: "memory");
        else              asm volatile("s_waitcnt vmcnt(0)" ::: "memory");
        __builtin_amdgcn_s_barrier();
        __builtin_amdgcn_sched_barrier(0);
        if (it + 2 < NIT) {
            const size_t kb = (size_t)(it + 2) * 64;   // 32 k * 2 B
            gld_lds16(gA + kb, As + of + lofs);
            gld_lds16(gB + kb, Bs + of + lofs);
        }
        const short* Ab = As + oc;
        const short* Bb = Bs + oc;
        bf16x8 af = *(const bf16x8*)&Ab[(w * 16 + l15) * 32 + quad * 8];
#pragma unroll
        for (int ni = 0; ni < 4; ni++) {
            bf16x8 bfr = *(const bf16x8*)&Bb[(ni * 16 + l15) * 32 + quad * 8];
            acc[ni] = __builtin_amdgcn_mfma_f32_16x16x32_bf16(af, bfr, acc[ni], 0, 0, 0);
        }
        int t = oc; oc = on; on = of; of = t;
    }
}

// ---------------------------------------------------------------------------
// 64x64 core with f32 A (optionally A+A2), cvt->bf16 during staging.
// ---------------------------------------------------------------------------
template<int K, bool ADD>
__device__ __forceinline__ void gemm_core_cvt64(const float* __restrict__ Af,
                                                const float* __restrict__ A2f,
                                                const __hip_bfloat16* __restrict__ Bt,
                                                int row0, int nb0, int lda, int ldb,
                                                short* As, short* Bs, floatx4 (&acc)[4])
{
    constexpr int NIT = K / 32;
    const int tid  = threadIdx.x;
    const int w    = tid >> 6;
    const int lane = tid & 63;
    const int quad = lane >> 4;
    const int l15  = lane & 15;

    const int o = w * 1024 + lane * 16;
    const char* gB = (const char*)Bt + (size_t)(nb0 + (o >> 6)) * ((size_t)ldb * 2) + (o & 63);
    const int lofs = w * 512;

    const int r0 = tid >> 3, k0 = (tid & 7) * 4;     // f32 index
    const float* gA0 = Af + (size_t)(row0 + r0) * lda + k0;        // rows 0..31
    const float* gA1 = gA0 + (size_t)32 * lda;                     // rows 32..63
    const float* gB0 = ADD ? (A2f + (size_t)(row0 + r0) * lda + k0) : nullptr;
    const float* gB1 = ADD ? (gB0 + (size_t)32 * lda) : nullptr;
    const int aofs0 = r0 * 32 + k0, aofs1 = aofs0 + 1024;

    float4 f0, f1;
    auto loadA = [&](int kt) {
        f0 = *(const float4*)(gA0 + kt);
        f1 = *(const float4*)(gA1 + kt);
        if (ADD) {
            float4 a = *(const float4*)(gB0 + kt);
            float4 b = *(const float4*)(gB1 + kt);
            f0.x += a.x; f0.y += a.y; f0.z += a.z; f0.w += a.w;
            f1.x += b.x; f1.y += b.y; f1.z += b.z; f1.w += b.w;
        }
    };
    auto writeA = [&](short* buf) {
        *(bh4*)&buf[aofs0] = pack4(f0);
        *(bh4*)&buf[aofs1] = pack4(f1);
    };

    loadA(0);
    gld_lds16(gB, Bs + lofs);
    writeA(As);

#pragma unroll 8
    for (int it = 0; it < NIT; ++it) {
        __syncthreads();
        const int cb = it & 1;
        const bool more = (it + 1 < NIT);
        if (more) {
            loadA((it + 1) * 32);
            gld_lds16(gB + (size_t)(it + 1) * 64, Bs + (cb ^ 1) * 2048 + lofs);
        }
        const short* Ab = As + cb * 2048;
        const short* Bb = Bs + cb * 2048;
        bf16x8 af = *(const bf16x8*)&Ab[(w * 16 + l15) * 32 + quad * 8];
#pragma unroll
        for (int ni = 0; ni < 4; ni++) {
            bf16x8 bfr = *(const bf16x8*)&Bb[(ni * 16 + l15) * 32 + quad * 8];
            acc[ni] = __builtin_amdgcn_mfma_f32_16x16x32_bf16(af, bfr, acc[ni], 0, 0, 0);
        }
        if (more) writeA(As + (cb ^ 1) * 2048);
    }
}

// ---------------------------------------------------------------------------
// Generic 64x64 GEMM (used for t2o only now), XCD-aware swizzle.
// EPI: 0 f32 (+bias); 1 bf16 (+bias); 2 relu -> bf16.
// ---------------------------------------------------------------------------
template<int K, int EPI, int COLS>
__global__ __launch_bounds__(256)
void mfma_gemm64(const __hip_bfloat16* __restrict__ A,
                 const __hip_bfloat16* __restrict__ Bt,
                 const float* __restrict__ bias,
                 float* __restrict__ outf, __hip_bfloat16* __restrict__ outb,
                 int lda, int ldb, int ldOut)
{
    __shared__ alignas(16) short As[3 * 2048];
    __shared__ alignas(16) short Bs[3 * 2048];

    constexpr int BPG = 8 * COLS;
    const int g  = blockIdx.x / BPG;
    const int wq = blockIdx.x % BPG;
    const int row0 = (g * 8 + (wq & 7)) * 64;
    const int nb0  = (wq >> 3) * 64;

    const int tid = threadIdx.x, w = tid >> 6, lane = tid & 63;
    const int quad = lane >> 4, l15 = lane & 15;

    floatx4 acc[4];
#pragma unroll
    for (int ni = 0; ni < 4; ni++) acc[ni] = (floatx4){0.f, 0.f, 0.f, 0.f};

    gemm_core64<K>(A, Bt, row0, nb0, lda, ldb, As, Bs, acc);

    float bias_c[4];
#pragma unroll
    for (int ni = 0; ni < 4; ni++) bias_c[ni] = bias ? bias[nb0 + ni * 16 + l15] : 0.f;

#pragma unroll
    for (int r = 0; r < 4; r++) {
        int row = row0 + w * 16 + quad * 4 + r;
        size_t rb = (size_t)row * ldOut + nb0;
#pragma unroll
        for (int ni = 0; ni < 4; ni++) {
            float v = acc[ni][r] + bias_c[ni];
            if (EPI == 2)      outb[rb + ni * 16 + l15] = __float2bfloat16(fmaxf(v, 0.f));
            else if (EPI == 1) outb[rb + ni * 16 + l15] = __float2bfloat16(v);
            else               outf[rb + ni * 16 + l15] = v;
        }
    }
}

// ---------------------------------------------------------------------------
// Merged value-projection + off/attn GEMM (64x64, fused f32 cvt staging).
// ---------------------------------------------------------------------------
__global__ __launch_bounds__(256)
void mfma_gemm_vq(const float* __restrict__ src,
                  const __hip_bfloat16* __restrict__ Wvt,
                  const float* __restrict__ b_value,
                  __hip_bfloat16* __restrict__ valueb,
                  const float* __restrict__ tgt, const float* __restrict__ qpos,
                  const __hip_bfloat16* __restrict__ Woat,
                  const float* __restrict__ b_off, const float* __restrict__ b_attn,
                  float* __restrict__ offb, float* __restrict__ attnb)
{
    __shared__ alignas(16) short As[2 * 2048];
    __shared__ alignas(16) short Bs[2 * 2048];

    const int id = blockIdx.x;
    const int tid = threadIdx.x, w = tid >> 6, lane = tid & 63;
    const int quad = lane >> 4, l15 = lane & 15;

    floatx4 acc[4];
#pragma unroll
    for (int ni = 0; ni < 4; ni++) acc[ni] = (floatx4){0.f, 0.f, 0.f, 0.f};

    if (id < VT64 * 4) {     // value part
        const int g = id >> 5, wq = id & 31;
        const int row0 = (g * 8 + (wq & 7)) * 64;
        const int nb0  = (wq >> 3) * 64;
        gemm_core_cvt64<256, false>(src, nullptr, Wvt, row0, nb0, 256, 256, As, Bs, acc);
        float bias_c[4];
#pragma unroll
        for (int ni = 0; ni < 4; ni++) bias_c[ni] = b_value[nb0 + ni * 16 + l15];
#pragma unroll
        for (int r = 0; r < 4; r++) {
            int row = row0 + w * 16 + quad * 4 + r;
            size_t rb = (size_t)row * 256 + nb0;
#pragma unroll
            for (int ni = 0; ni < 4; ni++)
                valueb[rb + ni * 16 + l15] = __float2bfloat16(acc[ni][r] + bias_c[ni]);
        }
        return;
    }

    const int oid = id - VT64 * 4;
    const int g = oid / 48, wq = oid % 48;
    const int row0 = (g * 8 + (wq & 7)) * 64;
    const int c = wq >> 3;   // 0..5

    if (c < 4) {             // offsets: cols c*64 of Woat, f32 out ld 256
        const int nb0 = c * 64;
        gemm_core_cvt64<256, true>(tgt, qpos, Woat, row0, nb0, 256, 256, As, Bs, acc);
        float bias_c[4];
#pragma unroll
        for (int ni = 0; ni < 4; ni++) bias_c[ni] = b_off[nb0 + ni * 16 + l15];
#pragma unroll
        for (int r = 0; r < 4; r++) {
            int row = row0 + w * 16 + quad * 4 + r;
            size_t rb = (size_t)row * 256 + nb0;
#pragma unroll
            for (int ni = 0; ni < 4; ni++)
                offb[rb + ni * 16 + l15] = acc[ni][r] + bias_c[ni];
        }
    } else {                 // attn: Woat rows 256 + (c-4)*64; softmax16
        const int c0 = (c - 4) * 64;
        gemm_core_cvt64<256, true>(tgt, qpos, Woat, row0, 256 + c0, 256, 256, As, Bs, acc);
        float bias_c[4];
#pragma unroll
        for (int ni = 0; ni < 4; ni++) bias_c[ni] = b_attn[c0 + ni * 16 + l15];
#pragma unroll
        for (int r = 0; r < 4; r++) {
            int row = row0 + w * 16 + quad * 4 + r;
            size_t rb = (size_t)row * 128 + c0;
#pragma unroll
            for (int ni = 0; ni < 4; ni++) {
                float v = acc[ni][r] + bias_c[ni];
                float m = v;
#pragma unroll
                for (int msk = 1; msk <= 8; msk <<= 1) m = fmaxf(m, __shfl_xor(m, msk));
                float e = __expf(v - m);
                float ssum = e;
#pragma unroll
                for (int msk = 1; msk <= 8; msk <<= 1) ssum += __shfl_xor(ssum, msk);
                attnb[rb + ni * 16 + l15] = e / ssum;
            }
        }
    }
}

// ---------------------------------------------------------------------------
// Fused FFN: out = relu(x@W1+b1)@W2 + b2. One block = 32 rows, 8 waves, 512 thr.
// Structure: NO per-K-step barriers, NO B staging. W1t/W2t are L2-resident
// (512 KB each, every block reads all of them), so B-fragments are loaded
// DIRECTLY to registers (per-lane 16B global_load), software-pipelined one
// K-step ahead; compiler inserts the vmcnt waits. LDS holds only:
//   xs: x tile 32x256 bf16 (16 KB), staged once via global_load_lds from a
//       PRE-SWIZZLED xb (LN1 stores xb[row][col ^ ((row&7)<<3)]) so the
//       ds_read_b128 A-fragment reads are bank-conflict-free;
//   hs: h tile 32x1024 bf16 (64 KB), written/read with the same XOR swizzle
//       (write: col^((row&7)<<3), read matches) -> conflict-free b128 reads.
// 80 KB LDS -> 2 blocks/CU. Exactly two __syncthreads() in the kernel.
// The h HBM round-trip (67 MB) of the old FFN1/FFN2 pair is eliminated.
// ---------------------------------------------------------------------------
__global__ __launch_bounds__(512)
void ffn_fused(const __hip_bfloat16* __restrict__ xb,
               const __hip_bfloat16* __restrict__ W1t,
               const float* __restrict__ b1,
               const __hip_bfloat16* __restrict__ W2t,
               const float* __restrict__ b2,
               float* __restrict__ outf)
{
    __shared__ alignas(16) short xs[32 * 256];       // 16 KB (swizzled content)
    __shared__ alignas(16) short hs[32 * 1024];      // 64 KB (swizzled content)

    const int tid  = threadIdx.x;
    const int w    = tid >> 6;
    const int lane = tid & 63;
    const int quad = lane >> 4;
    const int l15  = lane & 15;
    const int row0 = blockIdx.x * 32;

    // ---- stage x (already swizzled in memory) linearly into LDS
    {
        const char* gx = (const char*)xb + (size_t)(row0 + (tid >> 5)) * 512 + (size_t)(tid & 31) * 16;
        char* dx = (char*)xs + (tid >> 6) * 1024;    // wave-uniform base (+lane*16 by HW)
        gld_lds16(gx, dx);
        gld_lds16(gx + 16 * 512, dx + 16 * 512);
    }
    __syncthreads();

    __hip_bfloat16* hsb = (__hip_bfloat16*)hs;

    // ---- phase 1: h[32][1024] = relu(x@W1+b1); wave w -> col chunks w, w+8
#pragma unroll
    for (int ci = 0; ci < 2; ci++) {
        const int c = w + ci * 8;
        // B fragment (n, kk): W1t row c*64 + n*16 + l15, bytes kk*64 + quad*16
        const char* gW = (const char*)W1t + (size_t)(c * 64 + l15) * 512 + (size_t)quad * 16;

        floatx4 acc[2][4];
#pragma unroll
        for (int m = 0; m < 2; m++)
#pragma unroll
            for (int n = 0; n < 4; n++) acc[m][n] = (floatx4){0.f, 0.f, 0.f, 0.f};

        bf16x8 bcur[4], bnxt[4];
#pragma unroll
        for (int n = 0; n < 4; n++)
            bcur[n] = *(const bf16x8*)(gW + (size_t)n * 8192);

#pragma unroll
        for (int kk = 0; kk < 8; kk++) {
            if (kk + 1 < 8) {
#pragma unroll
                for (int n = 0; n < 4; n++)
                    bnxt[n] = *(const bf16x8*)(gW + (size_t)n * 8192 + (size_t)(kk + 1) * 64);
            }
            const int ac = (kk * 32 + quad * 8) ^ ((l15 & 7) << 3);   // swizzled col
            bf16x8 a0 = *(const bf16x8*)&xs[(0 * 16 + l15) * 256 + ac];
            bf16x8 a1 = *(const bf16x8*)&xs[(1 * 16 + l15) * 256 + ac];
#pragma unroll
            for (int n = 0; n < 4; n++) {
                acc[0][n] = __builtin_amdgcn_mfma_f32_16x16x32_bf16(a0, bcur[n], acc[0][n], 0, 0, 0);
                acc[1][n] = __builtin_amdgcn_mfma_f32_16x16x32_bf16(a1, bcur[n], acc[1][n], 0, 0, 0);
            }
#pragma unroll
            for (int n = 0; n < 4; n++) bcur[n] = bnxt[n];
        }

        // write h chunk: relu + bf16, swizzled cols (matching read XOR)
#pragma unroll
        for (int n = 0; n < 4; n++) {
            const int hc = c * 64 + n * 16 + l15;
            const float bb = b1[hc];
#pragma unroll
            for (int m = 0; m < 2; m++)
#pragma unroll
                for (int r = 0; r < 4; r++) {
                    const int hr = m * 16 + quad * 4 + r;
                    hsb[hr * 1024 + (hc ^ ((hr & 7) << 3))] =
                        __float2bfloat16(fmaxf(acc[m][n][r] + bb, 0.f));
                }
        }
    }

    __syncthreads();

    // ---- phase 2: out[32][256] = h@W2 + b2; wave w -> cols w*32..w*32+31
    const char* gW2 = (const char*)W2t + (size_t)(w * 32 + l15) * 2048 + (size_t)quad * 16;

    floatx4 acc2[2][2];
#pragma unroll
    for (int m = 0; m < 2; m++)
#pragma unroll
        for (int n = 0; n < 2; n++) acc2[m][n] = (floatx4){0.f, 0.f, 0.f, 0.f};

    bf16x8 c0[2], c1[2];
#pragma unroll
    for (int n = 0; n < 2; n++)
        c0[n] = *(const bf16x8*)(gW2 + (size_t)n * 32768);

#pragma unroll
    for (int kk = 0; kk < 32; kk++) {
        if (kk + 1 < 32) {
#pragma unroll
            for (int n = 0; n < 2; n++)
                c1[n] = *(const bf16x8*)(gW2 + (size_t)n * 32768 + (size_t)(kk + 1) * 64);
        }
        const int ac = (kk * 32 + quad * 8) ^ ((l15 & 7) << 3);
        bf16x8 a0 = *(const bf16x8*)&hs[(0 * 16 + l15) * 1024 + ac];
        bf16x8 a1 = *(const bf16x8*)&hs[(1 * 16 + l15) * 1024 + ac];
#pragma unroll
        for (int n = 0; n < 2; n++) {
            acc2[0][n] = __builtin_amdgcn_mfma_f32_16x16x32_bf16(a0, c0[n], acc2[0][n], 0, 0, 0);
            acc2[1][n] = __builtin_amdgcn_mfma_f32_16x16x32_bf16(a1, c0[n], acc2[1][n], 0, 0, 0);
        }
#pragma unroll
        for (int n = 0; n < 2; n++) c0[n] = c1[n];
    }

    // epilogue: f32 out + b2
#pragma unroll
    for (int n = 0; n < 2; n++) {
        const int col = w * 32 + n * 16 + l15;
        const float bb = b2[col];
#pragma unroll
        for (int m = 0; m < 2; m++)
#pragma unroll
            for (int r = 0; r < 4; r++) {
                const int row = row0 + m * 16 + quad * 4 + r;
                outf[(size_t)row * 256 + col] = acc2[m][n][r] + bb;
            }
    }
}

// ---------------------------------------------------------------------------
// Residual + LayerNorm, one wave per 256-col row.
// v = resid + in1 (+ in2) (+ bias). B1: in1 is bf16.
// NOTE: the bf16 output (outb) is stored PRE-SWIZZLED for ffn_fused:
//   xb[row][col ^ ((row&7)<<3)] (XOR on bits 3-5 keeps bh4 groups intact).
//   outb's ONLY consumer is ffn_fused.
// ---------------------------------------------------------------------------
template<bool B1>
__global__ __launch_bounds__(256)
void ln_kernel(const float* __restrict__ in1f, const __hip_bfloat16* __restrict__ in1b,
               const float* __restrict__ in2,
               const float* __restrict__ resid, const float* __restrict__ bias,
               const float* __restrict__ g, const float* __restrict__ b,
               float* __restrict__ outf, __hip_bfloat16* __restrict__ outb)
{
    const int row  = blockIdx.x * 4 + (threadIdx.x >> 6);
    const int lane = threadIdx.x & 63;
    const size_t rb = (size_t)row * 256 + lane * 4;

    float4 v = *(const float4*)(resid + rb);
    if (B1) {
        bh4 a = *(const bh4*)(in1b + rb);
        v.x += __bfloat162float(a.a); v.y += __bfloat162float(a.b);
        v.z += __bfloat162float(a.c); v.w += __bfloat162float(a.d);
    } else {
        float4 a = *(const float4*)(in1f + rb);
        v.x += a.x; v.y += a.y; v.z += a.z; v.w += a.w;
    }
    if (in2) {
        float4 c = *(const float4*)(in2 + rb);
        v.x += c.x; v.y += c.y; v.z += c.z; v.w += c.w;
    }
    if (bias) {
        float4 c = *(const float4*)(bias + lane * 4);
        v.x += c.x; v.y += c.y; v.z += c.z; v.w += c.w;
    }
    float s  = v.x + v.y + v.z + v.w;
    float sq = v.x * v.x + v.y * v.y + v.z * v.z + v.w * v.w;
#pragma unroll
    for (int msk = 1; msk <= 32; msk <<= 1) {
        s += __shfl_xor(s, msk); sq += __shfl_xor(sq, msk);
    }
    float mean = s * (1.f / 256.f);
    float var  = sq * (1.f / 256.f) - mean * mean;
    float rstd = rsqrtf(var + 1e-5f);
    float4 gg = *(const float4*)(g + lane * 4);
    float4 bb = *(const float4*)(b + lane * 4);
    float4 o;
    o.x = (v.x - mean) * rstd * gg.x + bb.x;
    o.y = (v.y - mean) * rstd * gg.y + bb.y;
    o.z = (v.z - mean) * rstd * gg.z + bb.z;
    o.w = (v.w - mean) * rstd * gg.w + bb.w;
    *(float4*)(outf + rb) = o;
    if (outb) {
        const int scol = (lane * 4) ^ ((row & 7) << 3);   // swizzle for ffn_fused
        *(bh4*)(outb + (size_t)row * 256 + scol) =
            { __float2bfloat16(o.x), __float2bfloat16(o.y),
              __float2bfloat16(o.z), __float2bfloat16(o.w) };
    }
}

// ---------------------------------------------------------------------------
// Prep: weight transpose + f32->bf16 only (736 tiles of 32x32)
// ---------------------------------------------------------------------------
__global__ __launch_bounds__(256)
void prep_kernel(const float* w0, const float* w1, const float* w2,
                 const float* w3, const float* w4, const float* w5,
                 __hip_bfloat16* o0, __hip_bfloat16* o1, __hip_bfloat16* o2,
                 __hip_bfloat16* o3, __hip_bfloat16* o4, __hip_bfloat16* o5)
{
    int t = blockIdx.x;
    const float* s; __hip_bfloat16* dst; int Kd, Nd, tl;
    if      (t < 64)  { s = w0; dst = o0; Kd = 256;  Nd = 256;  tl = t; }
    else if (t < 128) { s = w1; dst = o1; Kd = 256;  Nd = 256;  tl = t - 64; }
    else if (t < 160) { s = w2; dst = o2; Kd = 256;  Nd = 128;  tl = t - 128; }
    else if (t < 224) { s = w3; dst = o3; Kd = 256;  Nd = 256;  tl = t - 160; }
    else if (t < 480) { s = w4; dst = o4; Kd = 256;  Nd = 1024; tl = t - 224; }
    else              { s = w5; dst = o5; Kd = 1024; Nd = 256;  tl = t - 480; }
    int ntn = Nd >> 5;
    int kt = tl / ntn, nt = tl - kt * ntn;
    __shared__ float T[32][33];
    int tx = threadIdx.x & 31, ty = threadIdx.x >> 5;
#pragma unroll
    for (int i = 0; i < 4; i++) {
        int k = kt * 32 + ty + i * 8;
        T[tx][ty + i * 8] = s[(size_t)k * Nd + nt * 32 + tx];
    }
    __syncthreads();
#pragma unroll
    for (int i = 0; i < 4; i++) {
        int n = nt * 32 + ty + i * 8;
        dst[(size_t)n * Kd + kt * 32 + tx] = __float2bfloat16(T[ty + i * 8][tx]);
    }
}

// ---------------------------------------------------------------------------
// Deformable bilinear sampling (R8 version, 44.7 us best). Block = 8 queries,
// LDS 4B/entry, stride-65, 16-deep batched 16B gathers.
// ---------------------------------------------------------------------------
#define QB 8
__global__ __launch_bounds__(256, 4)
void sample_kernel(const float* __restrict__ refp, const float* __restrict__ offb,
                   const float* __restrict__ attn,
                   const __hip_bfloat16* __restrict__ value,
                   __hip_bfloat16* __restrict__ tgt2)
{
    __shared__ unsigned spk[64 * 65];       // [sc=lp*4+c][g=ql*8+h]

    const int q0  = blockIdx.x * QB;
    const int tid = threadIdx.x;

#pragma unroll
    for (int k = 0; k < 4; k++) {
        const int it = tid + k * 256;        // (ql,h,lp)
        const int ql = it >> 7, h = (it >> 4) & 7, lp = it & 15;
        const int l = lp >> 2, p = lp & 3;
        const int q = q0 + ql, b = q >> 13;
        const int Wl = 128 >> l;
        const int LST = (l == 0) ? 0 : (l == 1) ? 16384 : (l == 2) ? 20480 : 21504;

        const float rx = refp[((size_t)q * N_LEVELS + l) * 2 + 0];
        const float ry = refp[((size_t)q * N_LEVELS + l) * 2 + 1];
        const float ox = offb[(size_t)q * 256 + h * 32 + l * 8 + p * 2 + 0];
        const float oy = offb[(size_t)q * 256 + h * 32 + l * 8 + p * 2 + 1];
        const float a  = attn[(size_t)q * 128 + h * 16 + lp];

        const float x = rx * Wl - 0.5f + ox;
        const float y = ry * Wl - 0.5f + oy;
        const float x0f = floorf(x), y0f = floorf(y);
        const float wx = x - x0f, wy = y - y0f;
        const int ix = (int)x0f, iy = (int)y0f;
        const int base = b * S_TOTAL + LST;
        const int g = ql * 8 + h;
        const float cw[4] = {(1.f - wx) * (1.f - wy) * a, wx * (1.f - wy) * a,
                             (1.f - wx) * wy * a,         wx * wy * a};
#pragma unroll
        for (int c = 0; c < 4; c++) {
            const int xi = ix + (c & 1), yi = iy + (c >> 1);
            const bool valid = ((unsigned)xi < (unsigned)Wl) && ((unsigned)yi < (unsigned)Wl);
            const unsigned pix = valid ? (unsigned)(base + yi * Wl + xi) : (unsigned)base;
            const __half hw = __float2half(valid ? cw[c] : 0.f);
            spk[(lp * 4 + c) * 65 + g] = (pix << 16) | (unsigned)__half_as_ushort(hw);
        }
    }
    __syncthreads();

    const int ql = tid >> 5, h = (tid >> 2) & 7, d4 = tid & 3;
    const int q = q0 + ql, g = ql * 8 + h;
    const int c0 = h * 32 + d4 * 8;
    const char* vb = (const char*)value + (size_t)c0 * 2;

    float ac[8] = {0.f, 0.f, 0.f, 0.f, 0.f, 0.f, 0.f, 0.f};
#pragma unroll
    for (int ch = 0; ch < 4; ch++) {
        unsigned us[16];
#pragma unroll
        for (int j = 0; j < 16; j++) us[j] = spk[(ch * 16 + j) * 65 + g];
        uint4 rv[16];
#pragma unroll
        for (int j = 0; j < 16; j++)
            rv[j] = *(const uint4*)(vb + ((size_t)(us[j] >> 16) << 9));
#pragma unroll
        for (int j = 0; j < 16; j++) {
            float wv = __half2float(__ushort_as_half((unsigned short)(us[j] & 0xffffu)));
            ac[0] += wv * __uint_as_float(rv[j].x << 16);
            ac[1] += wv * __uint_as_float(rv[j].x & 0xffff0000u);
            ac[2] += wv * __uint_as_float(rv[j].y << 16);
            ac[3] += wv * __uint_as_float(rv[j].y & 0xffff0000u);
            ac[4] += wv * __uint_as_float(rv[j].z << 16);
            ac[5] += wv * __uint_as_float(rv[j].z & 0xffff0000u);
            ac[6] += wv * __uint_as_float(rv[j].w << 16);
            ac[7] += wv * __uint_as_float(rv[j].w & 0xffff0000u);
        }
    }
    bh8 o;
#pragma unroll
    for (int i = 0; i < 8; i++) o.v[i] = __float2bfloat16(ac[i]);
    *(bh8*)(tgt2 + (size_t)q * 256 + c0) = o;
}

// ---------------------------------------------------------------------------
extern "C" void kernel_launch(void* const* d_in, const int* in_sizes, int n_in,
                              void* d_out, int out_size, void* d_ws, size_t ws_size,
                              hipStream_t stream) {
    const float* tgt     = (const float*)d_in[0];
    const float* qpos    = (const float*)d_in[1];
    const float* refp    = (const float*)d_in[2];
    const float* src     = (const float*)d_in[3];
    const float* W_value = (const float*)d_in[6];
    const float* b_value = (const float*)d_in[7];
    const float* W_off   = (const float*)d_in[8];
    const float* b_off   = (const float*)d_in[9];
    const float* W_attn  = (const float*)d_in[10];
    const float* b_attn  = (const float*)d_in[11];
    const float* W_out   = (const float*)d_in[12];
    const float* b_out   = (const float*)d_in[13];
    const float* ln1_g   = (const float*)d_in[14];
    const float* ln1_b   = (const float*)d_in[15];
    const float* W1      = (const float*)d_in[16];
    const float* b1      = (const float*)d_in[17];
    const float* W2      = (const float*)d_in[18];
    const float* b2      = (const float*)d_in[19];
    const float* ln3_g   = (const float*)d_in[20];
    const float* ln3_b   = (const float*)d_in[21];
    float* out = (float*)d_out;

    // workspace layout
    char* p = (char*)d_ws;
    auto nxt = [&](size_t b) { char* r = p; p += (b + 255) & ~(size_t)255; return r; };
    __hip_bfloat16* Wvt    = (__hip_bfloat16*)nxt((size_t)256 * 256 * 2);
    __hip_bfloat16* Woat   = (__hip_bfloat16*)nxt((size_t)384 * 256 * 2);
    __hip_bfloat16* Woutt  = (__hip_bfloat16*)nxt((size_t)256 * 256 * 2);
    __hip_bfloat16* W1t    = (__hip_bfloat16*)nxt((size_t)1024 * 256 * 2);
    __hip_bfloat16* W2t    = (__hip_bfloat16*)nxt((size_t)256 * 1024 * 2);
    __hip_bfloat16* valueb = (__hip_bfloat16*)nxt((size_t)M_V * 256 * 2);  // dead after sampler
    float*          offb   = (float*)nxt((size_t)M_Q * 256 * 4);           // dead after sampler
    float*          attnb  = (float*)nxt((size_t)M_Q * 128 * 4);
    __hip_bfloat16* tgt2b  = (__hip_bfloat16*)nxt((size_t)M_Q * 256 * 2);
    __hip_bfloat16* t2ob   = (__hip_bfloat16*)nxt((size_t)M_Q * 256 * 2);
    float*          x      = (float*)nxt((size_t)M_Q * 256 * 4);
    __hip_bfloat16* xb     = (__hip_bfloat16*)nxt((size_t)M_Q * 256 * 2);  // SWIZZLED (ffn only)
    // FFN2 output (f32, 16.8 MB) overlays valueb (dead after sampler)
    float* f2o = (float*)valueb;

    dim3 blk(256);

    // 0) prep: weight transpose+cvt only
    prep_kernel<<<dim3(736), blk, 0, stream>>>(
        W_value, W_off, W_attn, W_out, W1, W2,
        Wvt, Woat, Woat + 256 * 256, Woutt, W1t, W2t);

    // 1) value GEMM ++ off/attn GEMM (64x64, fused cvt, XCD swizzle)
    mfma_gemm_vq<<<dim3(VT64 * 4 + 256 / 8 * 48), blk, 0, stream>>>(
        src, Wvt, b_value, valueb, tgt, qpos, Woat, b_off, b_attn, offb, attnb);

    // 2) deformable sampling -> tgt2 (bf16)
    sample_kernel<<<dim3(M_Q / QB), blk, 0, stream>>>(refp, offb, attnb, valueb, tgt2b);

    // 3) t2o = tgt2 @ W_out + b_out -> bf16  (COLS=4, 1024 blocks)
    mfma_gemm64<256, 1, 4><<<dim3(M_Q / 64 * 4), blk, 0, stream>>>(
        tgt2b, Woutt, b_out, nullptr, t2ob, 256, 256, 256);

    // 4) x = LN1(tgt + t2o) -> f32 + swizzled bf16
    ln_kernel<true><<<dim3(M_Q / 4), blk, 0, stream>>>(
        nullptr, t2ob, nullptr, tgt, nullptr, ln1_g, ln1_b, x, xb);

    // 5+6) fused FFN: f2o = relu(xb@W1+b1)@W2 + b2   (512 blocks x 512 thr)
    ffn_fused<<<dim3(M_Q / 32), dim3(512), 0, stream>>>(
        xb, W1t, b1, W2t, b2, f2o);

    // 7) out = LN3(x + f2o) -> f32
    ln_kernel<false><<<dim3(M_Q / 4), blk, 0, stream>>>(
        f2o, nullptr, nullptr, x, nullptr, ln3_g, ln3_b, out, nullptr);
}

// Round 9
// 315.898 us; speedup vs baseline: 1.0015x; 1.0015x over previous
//
#include <hip/hip_runtime.h>
#include <hip/hip_bf16.h>
#include <hip/hip_fp16.h>
#include <math.h>

// Problem constants (fixed by setup_inputs)
#define D_MODEL   256
#define D_FFN     1024
#define N_LEVELS  4
#define N_HEADS   8
#define N_POINTS  4
#define BATCH     2
#define LQ        8192
#define S_TOTAL   21760            // 128*128 + 64*64 + 32*32 + 16*16
#define M_Q       (BATCH*LQ)       // 16384
#define M_V       (BATCH*S_TOTAL)  // 43520
#define VT64      (M_V/64)         // 680 row tiles for value GEMM

typedef __attribute__((ext_vector_type(8))) short bf16x8;   // 8 bf16 = 4 VGPRs
typedef __attribute__((ext_vector_type(4))) float floatx4;  // mfma C/D

struct alignas(8)  bh4 { __hip_bfloat16 a, b, c, d; };
struct alignas(16) bh8 { __hip_bfloat16 v[8]; };

__device__ __forceinline__ void gld_lds16(const void* g, void* l) {
    __builtin_amdgcn_global_load_lds(
        (const __attribute__((address_space(1))) void*)g,
        (__attribute__((address_space(3))) void*)l, 16, 0, 0);
}

__device__ __forceinline__ bh4 pack4(float4 a) {
    return { __float2bfloat16(a.x), __float2bfloat16(a.y),
             __float2bfloat16(a.z), __float2bfloat16(a.w) };
}

// ---------------------------------------------------------------------------
// 64x64 bf16 MFMA core (R3 version: triple-buffer, distance-2 counted vmcnt).
// ---------------------------------------------------------------------------
template<int K>
__device__ __forceinline__ void gemm_core64(const __hip_bfloat16* __restrict__ A,
                                            const __hip_bfloat16* __restrict__ Bt,
                                            int row0, int nb0, int lda, int ldb,
                                            short* As, short* Bs, floatx4 (&acc)[4])
{
    constexpr int NIT = K / 32;
    static_assert(NIT >= 2, "");
    const int tid  = threadIdx.x;
    const int w    = tid >> 6;
    const int lane = tid & 63;
    const int quad = lane >> 4;
    const int l15  = lane & 15;
    const size_t ldaB = (size_t)lda * 2, ldbB = (size_t)ldb * 2;

    const int o = w * 1024 + lane * 16;          // byte offset in 4KB tile
    const char* gA = (const char*)A + (size_t)(row0 + (o >> 6)) * ldaB + (o & 63);
    const char* gB = (const char*)Bt + (size_t)(nb0 + (o >> 6)) * ldbB + (o & 63);
    const int lofs = w * 512;                    // shorts

    gld_lds16(gA,      As + lofs);
    gld_lds16(gB,      Bs + lofs);
    gld_lds16(gA + 64, As + 2048 + lofs);
    gld_lds16(gB + 64, Bs + 2048 + lofs);

    int oc = 0, on = 2048, of = 4096;            // cur / next / far buffer offsets
#pragma unroll
    for (int it = 0; it < NIT; ++it) {
        if (it + 1 < NIT) asm volatile("s_waitcnt vmcnt(2)" ::: "memory");
        else              asm volatile("s_waitcnt vmcnt(0)" ::: "memory");
        __builtin_amdgcn_s_barrier();
        __builtin_amdgcn_sched_barrier(0);
        if (it + 2 < NIT) {
            const size_t kb = (size_t)(it + 2) * 64;   // 32 k * 2 B
            gld_lds16(gA + kb, As + of + lofs);
            gld_lds16(gB + kb, Bs + of + lofs);
        }
        const short* Ab = As + oc;
        const short* Bb = Bs + oc;
        bf16x8 af = *(const bf16x8*)&Ab[(w * 16 + l15) * 32 + quad * 8];
#pragma unroll
        for (int ni = 0; ni < 4; ni++) {
            bf16x8 bfr = *(const bf16x8*)&Bb[(ni * 16 + l15) * 32 + quad * 8];
            acc[ni] = __builtin_amdgcn_mfma_f32_16x16x32_bf16(af, bfr, acc[ni], 0, 0, 0);
        }
        int t = oc; oc = on; on = of; of = t;
    }
}

// ---------------------------------------------------------------------------
// 64x64 core with f32 A (optionally A+A2), cvt->bf16 during staging.
// ---------------------------------------------------------------------------
template<int K, bool ADD>
__device__ __forceinline__ void gemm_core_cvt64(const float* __restrict__ Af,
                                                const float* __restrict__ A2f,
                                                const __hip_bfloat16* __restrict__ Bt,
                                                int row0, int nb0, int lda, int ldb,
                                                short* As, short* Bs, floatx4 (&acc)[4])
{
    constexpr int NIT = K / 32;
    const int tid  = threadIdx.x;
    const int w    = tid >> 6;
    const int lane = tid & 63;
    const int quad = lane >> 4;
    const int l15  = lane & 15;

    const int o = w * 1024 + lane * 16;
    const char* gB = (const char*)Bt + (size_t)(nb0 + (o >> 6)) * ((size_t)ldb * 2) + (o & 63);
    const int lofs = w * 512;

    const int r0 = tid >> 3, k0 = (tid & 7) * 4;     // f32 index
    const float* gA0 = Af + (size_t)(row0 + r0) * lda + k0;        // rows 0..31
    const float* gA1 = gA0 + (size_t)32 * lda;                     // rows 32..63
    const float* gB0 = ADD ? (A2f + (size_t)(row0 + r0) * lda + k0) : nullptr;
    const float* gB1 = ADD ? (gB0 + (size_t)32 * lda) : nullptr;
    const int aofs0 = r0 * 32 + k0, aofs1 = aofs0 + 1024;

    float4 f0, f1;
    auto loadA = [&](int kt) {
        f0 = *(const float4*)(gA0 + kt);
        f1 = *(const float4*)(gA1 + kt);
        if (ADD) {
            float4 a = *(const float4*)(gB0 + kt);
            float4 b = *(const float4*)(gB1 + kt);
            f0.x += a.x; f0.y += a.y; f0.z += a.z; f0.w += a.w;
            f1.x += b.x; f1.y += b.y; f1.z += b.z; f1.w += b.w;
        }
    };
    auto writeA = [&](short* buf) {
        *(bh4*)&buf[aofs0] = pack4(f0);
        *(bh4*)&buf[aofs1] = pack4(f1);
    };

    loadA(0);
    gld_lds16(gB, Bs + lofs);
    writeA(As);

#pragma unroll 8
    for (int it = 0; it < NIT; ++it) {
        __syncthreads();
        const int cb = it & 1;
        const bool more = (it + 1 < NIT);
        if (more) {
            loadA((it + 1) * 32);
            gld_lds16(gB + (size_t)(it + 1) * 64, Bs + (cb ^ 1) * 2048 + lofs);
        }
        const short* Ab = As + cb * 2048;
        const short* Bb = Bs + cb * 2048;
        bf16x8 af = *(const bf16x8*)&Ab[(w * 16 + l15) * 32 + quad * 8];
#pragma unroll
        for (int ni = 0; ni < 4; ni++) {
            bf16x8 bfr = *(const bf16x8*)&Bb[(ni * 16 + l15) * 32 + quad * 8];
            acc[ni] = __builtin_amdgcn_mfma_f32_16x16x32_bf16(af, bfr, acc[ni], 0, 0, 0);
        }
        if (more) writeA(As + (cb ^ 1) * 2048);
    }
}

// ---------------------------------------------------------------------------
// Generic 64x64 GEMM (t2o only), XCD-aware swizzle.
// EPI: 0 f32 (+bias); 1 bf16 (+bias); 2 relu -> bf16.
// ---------------------------------------------------------------------------
template<int K, int EPI, int COLS>
__global__ __launch_bounds__(256)
void mfma_gemm64(const __hip_bfloat16* __restrict__ A,
                 const __hip_bfloat16* __restrict__ Bt,
                 const float* __restrict__ bias,
                 float* __restrict__ outf, __hip_bfloat16* __restrict__ outb,
                 int lda, int ldb, int ldOut)
{
    __shared__ alignas(16) short As[3 * 2048];
    __shared__ alignas(16) short Bs[3 * 2048];

    constexpr int BPG = 8 * COLS;
    const int g  = blockIdx.x / BPG;
    const int wq = blockIdx.x % BPG;
    const int row0 = (g * 8 + (wq & 7)) * 64;
    const int nb0  = (wq >> 3) * 64;

    const int tid = threadIdx.x, w = tid >> 6, lane = tid & 63;
    const int quad = lane >> 4, l15 = lane & 15;

    floatx4 acc[4];
#pragma unroll
    for (int ni = 0; ni < 4; ni++) acc[ni] = (floatx4){0.f, 0.f, 0.f, 0.f};

    gemm_core64<K>(A, Bt, row0, nb0, lda, ldb, As, Bs, acc);

    float bias_c[4];
#pragma unroll
    for (int ni = 0; ni < 4; ni++) bias_c[ni] = bias ? bias[nb0 + ni * 16 + l15] : 0.f;

#pragma unroll
    for (int r = 0; r < 4; r++) {
        int row = row0 + w * 16 + quad * 4 + r;
        size_t rb = (size_t)row * ldOut + nb0;
#pragma unroll
        for (int ni = 0; ni < 4; ni++) {
            float v = acc[ni][r] + bias_c[ni];
            if (EPI == 2)      outb[rb + ni * 16 + l15] = __float2bfloat16(fmaxf(v, 0.f));
            else if (EPI == 1) outb[rb + ni * 16 + l15] = __float2bfloat16(v);
            else               outf[rb + ni * 16 + l15] = v;
        }
    }
}

// ---------------------------------------------------------------------------
// Merged value-projection + off/attn GEMM (64x64, fused f32 cvt staging).
// ---------------------------------------------------------------------------
__global__ __launch_bounds__(256)
void mfma_gemm_vq(const float* __restrict__ src,
                  const __hip_bfloat16* __restrict__ Wvt,
                  const float* __restrict__ b_value,
                  __hip_bfloat16* __restrict__ valueb,
                  const float* __restrict__ tgt, const float* __restrict__ qpos,
                  const __hip_bfloat16* __restrict__ Woat,
                  const float* __restrict__ b_off, const float* __restrict__ b_attn,
                  float* __restrict__ offb, float* __restrict__ attnb)
{
    __shared__ alignas(16) short As[2 * 2048];
    __shared__ alignas(16) short Bs[2 * 2048];

    const int id = blockIdx.x;
    const int tid = threadIdx.x, w = tid >> 6, lane = tid & 63;
    const int quad = lane >> 4, l15 = lane & 15;

    floatx4 acc[4];
#pragma unroll
    for (int ni = 0; ni < 4; ni++) acc[ni] = (floatx4){0.f, 0.f, 0.f, 0.f};

    if (id < VT64 * 4) {     // value part
        const int g = id >> 5, wq = id & 31;
        const int row0 = (g * 8 + (wq & 7)) * 64;
        const int nb0  = (wq >> 3) * 64;
        gemm_core_cvt64<256, false>(src, nullptr, Wvt, row0, nb0, 256, 256, As, Bs, acc);
        float bias_c[4];
#pragma unroll
        for (int ni = 0; ni < 4; ni++) bias_c[ni] = b_value[nb0 + ni * 16 + l15];
#pragma unroll
        for (int r = 0; r < 4; r++) {
            int row = row0 + w * 16 + quad * 4 + r;
            size_t rb = (size_t)row * 256 + nb0;
#pragma unroll
            for (int ni = 0; ni < 4; ni++)
                valueb[rb + ni * 16 + l15] = __float2bfloat16(acc[ni][r] + bias_c[ni]);
        }
        return;
    }

    const int oid = id - VT64 * 4;
    const int g = oid / 48, wq = oid % 48;
    const int row0 = (g * 8 + (wq & 7)) * 64;
    const int c = wq >> 3;   // 0..5

    if (c < 4) {             // offsets: cols c*64 of Woat, f32 out ld 256
        const int nb0 = c * 64;
        gemm_core_cvt64<256, true>(tgt, qpos, Woat, row0, nb0, 256, 256, As, Bs, acc);
        float bias_c[4];
#pragma unroll
        for (int ni = 0; ni < 4; ni++) bias_c[ni] = b_off[nb0 + ni * 16 + l15];
#pragma unroll
        for (int r = 0; r < 4; r++) {
            int row = row0 + w * 16 + quad * 4 + r;
            size_t rb = (size_t)row * 256 + nb0;
#pragma unroll
            for (int ni = 0; ni < 4; ni++)
                offb[rb + ni * 16 + l15] = acc[ni][r] + bias_c[ni];
        }
    } else {                 // attn: Woat rows 256 + (c-4)*64; softmax16
        const int c0 = (c - 4) * 64;
        gemm_core_cvt64<256, true>(tgt, qpos, Woat, row0, 256 + c0, 256, 256, As, Bs, acc);
        float bias_c[4];
#pragma unroll
        for (int ni = 0; ni < 4; ni++) bias_c[ni] = b_attn[c0 + ni * 16 + l15];
#pragma unroll
        for (int r = 0; r < 4; r++) {
            int row = row0 + w * 16 + quad * 4 + r;
            size_t rb = (size_t)row * 128 + c0;
#pragma unroll
            for (int ni = 0; ni < 4; ni++) {
                float v = acc[ni][r] + bias_c[ni];
                float m = v;
#pragma unroll
                for (int msk = 1; msk <= 8; msk <<= 1) m = fmaxf(m, __shfl_xor(m, msk));
                float e = __expf(v - m);
                float ssum = e;
#pragma unroll
                for (int msk = 1; msk <= 8; msk <<= 1) ssum += __shfl_xor(ssum, msk);
                attnb[rb + ni * 16 + l15] = e / ssum;
            }
        }
    }
}

// ---------------------------------------------------------------------------
// Fused FFN + LN3: out = LN3(x + relu(x@W1+b1)@W2 + b2).
// One block = 32 rows, 8 waves, 512 thr. R7 measured the distance-1 version
// at 66.4 us, MfmaUtil 9.5% -> L2-latency-bound. Changes:
//  * B prefetch distance 2 (phase1) / 3 (phase2) via rotating reg buffers
//    (indices compile-time; __launch_bounds__(512,4) pins VGPR<=128 so the
//    2-blocks/CU LDS occupancy is preserved).
//  * s_setprio(1) around MFMA clusters (barrier-free waves drift -> m191
//    regime where setprio pays).
//  * LN3 fused: block owns 32 complete rows; pre-LN tile stashed in LDS
//    (hs reused as f32 [32][260]), per-wave 64-lane shfl LN, writes `out`
//    directly. Kills the LN3 dispatch + f2o 33.6MB HBM round-trip.
// ---------------------------------------------------------------------------
__global__ __launch_bounds__(512, 4)
void ffn_fused(const __hip_bfloat16* __restrict__ xb,
               const __hip_bfloat16* __restrict__ W1t,
               const float* __restrict__ b1,
               const __hip_bfloat16* __restrict__ W2t,
               const float* __restrict__ b2,
               const float* __restrict__ x,
               const float* __restrict__ ln_g, const float* __restrict__ ln_b,
               float* __restrict__ outf)
{
    __shared__ alignas(16) short xs[32 * 256];       // 16 KB (swizzled content)
    __shared__ alignas(16) short hs[32 * 1024];      // 64 KB (swizzled h / f32 out)

    const int tid  = threadIdx.x;
    const int w    = tid >> 6;
    const int lane = tid & 63;
    const int quad = lane >> 4;
    const int l15  = lane & 15;
    const int row0 = blockIdx.x * 32;

    // ---- stage x (already swizzled in memory) linearly into LDS
    {
        const char* gx = (const char*)xb + (size_t)(row0 + (tid >> 5)) * 512 + (size_t)(tid & 31) * 16;
        char* dx = (char*)xs + (tid >> 6) * 1024;    // wave-uniform base (+lane*16 by HW)
        gld_lds16(gx, dx);
        gld_lds16(gx + 16 * 512, dx + 16 * 512);
    }
    __syncthreads();

    __hip_bfloat16* hsb = (__hip_bfloat16*)hs;

    // ---- phase 1: h[32][1024] = relu(x@W1+b1); wave w -> col chunks w, w+8
#pragma unroll
    for (int ci = 0; ci < 2; ci++) {
        const int c = w + ci * 8;
        // B fragment (n, kk): W1t row c*64 + n*16 + l15, bytes kk*64 + quad*16
        const char* gW = (const char*)W1t + (size_t)(c * 64 + l15) * 512 + (size_t)quad * 16;

        floatx4 acc[2][4];
#pragma unroll
        for (int m = 0; m < 2; m++)
#pragma unroll
            for (int n = 0; n < 4; n++) acc[m][n] = (floatx4){0.f, 0.f, 0.f, 0.f};

        bf16x8 bq[3][4];                 // rotating, distance-2 prefetch
#pragma unroll
        for (int n = 0; n < 4; n++) {
            bq[0][n] = *(const bf16x8*)(gW + (size_t)n * 8192);
            bq[1][n] = *(const bf16x8*)(gW + (size_t)n * 8192 + 64);
        }

#pragma unroll
        for (int kk = 0; kk < 8; kk++) {
            if (kk + 2 < 8) {
#pragma unroll
                for (int n = 0; n < 4; n++)
                    bq[(kk + 2) % 3][n] = *(const bf16x8*)(gW + (size_t)n * 8192 + (size_t)(kk + 2) * 64);
            }
            const int ac = (kk * 32 + quad * 8) ^ ((l15 & 7) << 3);   // swizzled col
            bf16x8 a0 = *(const bf16x8*)&xs[l15 * 256 + ac];
            bf16x8 a1 = *(const bf16x8*)&xs[(16 + l15) * 256 + ac];
            __builtin_amdgcn_s_setprio(1);
#pragma unroll
            for (int n = 0; n < 4; n++) {
                acc[0][n] = __builtin_amdgcn_mfma_f32_16x16x32_bf16(a0, bq[kk % 3][n], acc[0][n], 0, 0, 0);
                acc[1][n] = __builtin_amdgcn_mfma_f32_16x16x32_bf16(a1, bq[kk % 3][n], acc[1][n], 0, 0, 0);
            }
            __builtin_amdgcn_s_setprio(0);
        }

        // write h chunk: relu + bf16, swizzled cols (matching read XOR)
#pragma unroll
        for (int n = 0; n < 4; n++) {
            const int hc = c * 64 + n * 16 + l15;
            const float bb = b1[hc];
#pragma unroll
            for (int m = 0; m < 2; m++)
#pragma unroll
                for (int r = 0; r < 4; r++) {
                    const int hr = m * 16 + quad * 4 + r;
                    hsb[hr * 1024 + (hc ^ ((hr & 7) << 3))] =
                        __float2bfloat16(fmaxf(acc[m][n][r] + bb, 0.f));
                }
        }
    }

    // ---- phase 2 B prologue: issue first 3 tiles BEFORE the barrier
    const char* gW2 = (const char*)W2t + (size_t)(w * 32 + l15) * 2048 + (size_t)quad * 16;
    bf16x8 b2q[4][2];                    // rotating, distance-3 prefetch
#pragma unroll
    for (int j = 0; j < 3; j++)
#pragma unroll
        for (int n = 0; n < 2; n++)
            b2q[j][n] = *(const bf16x8*)(gW2 + (size_t)n * 32768 + (size_t)j * 64);

    asm volatile("s_waitcnt lgkmcnt(0)" ::: "memory");   // h ds_writes landed
    __builtin_amdgcn_s_barrier();                        // vmem stays in flight
    __builtin_amdgcn_sched_barrier(0);

    // ---- phase 2: pre-LN out[32][256] = h@W2 + b2
    floatx4 acc2[2][2];
#pragma unroll
    for (int m = 0; m < 2; m++)
#pragma unroll
        for (int n = 0; n < 2; n++) acc2[m][n] = (floatx4){0.f, 0.f, 0.f, 0.f};

#pragma unroll
    for (int kk = 0; kk < 32; kk++) {
        if (kk + 3 < 32) {
#pragma unroll
            for (int n = 0; n < 2; n++)
                b2q[(kk + 3) & 3][n] = *(const bf16x8*)(gW2 + (size_t)n * 32768 + (size_t)(kk + 3) * 64);
        }
        const int ac = (kk * 32 + quad * 8) ^ ((l15 & 7) << 3);
        bf16x8 a0 = *(const bf16x8*)&hs[l15 * 1024 + ac];
        bf16x8 a1 = *(const bf16x8*)&hs[(16 + l15) * 1024 + ac];
        __builtin_amdgcn_s_setprio(1);
#pragma unroll
        for (int n = 0; n < 2; n++) {
            acc2[0][n] = __builtin_amdgcn_mfma_f32_16x16x32_bf16(a0, b2q[kk & 3][n], acc2[0][n], 0, 0, 0);
            acc2[1][n] = __builtin_amdgcn_mfma_f32_16x16x32_bf16(a1, b2q[kk & 3][n], acc2[1][n], 0, 0, 0);
        }
        __builtin_amdgcn_s_setprio(0);
    }

    // ---- stash pre-LN tile into LDS (reuse hs as f32 [32][260]; row base
    // 1040 B keeps float4 alignment; write pattern is 2-way/bank = free)
    __syncthreads();                     // all hs reads done before overwrite
    float* osh = (float*)hs;
#pragma unroll
    for (int n = 0; n < 2; n++) {
        const int col = w * 32 + n * 16 + l15;
        const float bb = b2[col];
#pragma unroll
        for (int m = 0; m < 2; m++)
#pragma unroll
            for (int r = 0; r < 4; r++) {
                const int row = m * 16 + quad * 4 + r;
                osh[row * 260 + col] = acc2[m][n][r] + bb;
            }
    }
    __syncthreads();

    // ---- fused LN3: wave w handles rows w*4 .. w*4+3
    float4 gg = *(const float4*)(ln_g + lane * 4);
    float4 bbv = *(const float4*)(ln_b + lane * 4);
#pragma unroll
    for (int rr = 0; rr < 4; rr++) {
        const int row = w * 4 + rr;
        float4 f = *(const float4*)&osh[row * 260 + lane * 4];
        float4 xr = *(const float4*)(x + (size_t)(row0 + row) * 256 + lane * 4);
        float4 v;
        v.x = f.x + xr.x; v.y = f.y + xr.y; v.z = f.z + xr.z; v.w = f.w + xr.w;
        float s  = v.x + v.y + v.z + v.w;
        float sq = v.x * v.x + v.y * v.y + v.z * v.z + v.w * v.w;
#pragma unroll
        for (int msk = 1; msk <= 32; msk <<= 1) {
            s += __shfl_xor(s, msk); sq += __shfl_xor(sq, msk);
        }
        float mean = s * (1.f / 256.f);
        float var  = sq * (1.f / 256.f) - mean * mean;
        float rstd = rsqrtf(var + 1e-5f);
        float4 o;
        o.x = (v.x - mean) * rstd * gg.x + bbv.x;
        o.y = (v.y - mean) * rstd * gg.y + bbv.y;
        o.z = (v.z - mean) * rstd * gg.z + bbv.z;
        o.w = (v.w - mean) * rstd * gg.w + bbv.w;
        *(float4*)(outf + (size_t)(row0 + row) * 256 + lane * 4) = o;
    }
}

// ---------------------------------------------------------------------------
// Residual + LayerNorm, one wave per 256-col row.
// v = resid + in1 (+ in2) (+ bias). B1: in1 is bf16.
// NOTE: the bf16 output (outb) is stored PRE-SWIZZLED for ffn_fused:
//   xb[row][col ^ ((row&7)<<3)] (XOR on bits 3-5 keeps bh4 groups intact).
//   outb's ONLY consumer is ffn_fused.
// ---------------------------------------------------------------------------
template<bool B1>
__global__ __launch_bounds__(256)
void ln_kernel(const float* __restrict__ in1f, const __hip_bfloat16* __restrict__ in1b,
               const float* __restrict__ in2,
               const float* __restrict__ resid, const float* __restrict__ bias,
               const float* __restrict__ g, const float* __restrict__ b,
               float* __restrict__ outf, __hip_bfloat16* __restrict__ outb)
{
    const int row  = blockIdx.x * 4 + (threadIdx.x >> 6);
    const int lane = threadIdx.x & 63;
    const size_t rb = (size_t)row * 256 + lane * 4;

    float4 v = *(const float4*)(resid + rb);
    if (B1) {
        bh4 a = *(const bh4*)(in1b + rb);
        v.x += __bfloat162float(a.a); v.y += __bfloat162float(a.b);
        v.z += __bfloat162float(a.c); v.w += __bfloat162float(a.d);
    } else {
        float4 a = *(const float4*)(in1f + rb);
        v.x += a.x; v.y += a.y; v.z += a.z; v.w += a.w;
    }
    if (in2) {
        float4 c = *(const float4*)(in2 + rb);
        v.x += c.x; v.y += c.y; v.z += c.z; v.w += c.w;
    }
    if (bias) {
        float4 c = *(const float4*)(bias + lane * 4);
        v.x += c.x; v.y += c.y; v.z += c.z; v.w += c.w;
    }
    float s  = v.x + v.y + v.z + v.w;
    float sq = v.x * v.x + v.y * v.y + v.z * v.z + v.w * v.w;
#pragma unroll
    for (int msk = 1; msk <= 32; msk <<= 1) {
        s += __shfl_xor(s, msk); sq += __shfl_xor(sq, msk);
    }
    float mean = s * (1.f / 256.f);
    float var  = sq * (1.f / 256.f) - mean * mean;
    float rstd = rsqrtf(var + 1e-5f);
    float4 gg = *(const float4*)(g + lane * 4);
    float4 bb = *(const float4*)(b + lane * 4);
    float4 o;
    o.x = (v.x - mean) * rstd * gg.x + bb.x;
    o.y = (v.y - mean) * rstd * gg.y + bb.y;
    o.z = (v.z - mean) * rstd * gg.z + bb.z;
    o.w = (v.w - mean) * rstd * gg.w + bb.w;
    *(float4*)(outf + rb) = o;
    if (outb) {
        const int scol = (lane * 4) ^ ((row & 7) << 3);   // swizzle for ffn_fused
        *(bh4*)(outb + (size_t)row * 256 + scol) =
            { __float2bfloat16(o.x), __float2bfloat16(o.y),
              __float2bfloat16(o.z), __float2bfloat16(o.w) };
    }
}

// ---------------------------------------------------------------------------
// Prep: weight transpose + f32->bf16 only (736 tiles of 32x32)
// ---------------------------------------------------------------------------
__global__ __launch_bounds__(256)
void prep_kernel(const float* w0, const float* w1, const float* w2,
                 const float* w3, const float* w4, const float* w5,
                 __hip_bfloat16* o0, __hip_bfloat16* o1, __hip_bfloat16* o2,
                 __hip_bfloat16* o3, __hip_bfloat16* o4, __hip_bfloat16* o5)
{
    int t = blockIdx.x;
    const float* s; __hip_bfloat16* dst; int Kd, Nd, tl;
    if      (t < 64)  { s = w0; dst = o0; Kd = 256;  Nd = 256;  tl = t; }
    else if (t < 128) { s = w1; dst = o1; Kd = 256;  Nd = 256;  tl = t - 64; }
    else if (t < 160) { s = w2; dst = o2; Kd = 256;  Nd = 128;  tl = t - 128; }
    else if (t < 224) { s = w3; dst = o3; Kd = 256;  Nd = 256;  tl = t - 160; }
    else if (t < 480) { s = w4; dst = o4; Kd = 256;  Nd = 1024; tl = t - 224; }
    else              { s = w5; dst = o5; Kd = 1024; Nd = 256;  tl = t - 480; }
    int ntn = Nd >> 5;
    int kt = tl / ntn, nt = tl - kt * ntn;
    __shared__ float T[32][33];
    int tx = threadIdx.x & 31, ty = threadIdx.x >> 5;
#pragma unroll
    for (int i = 0; i < 4; i++) {
        int k = kt * 32 + ty + i * 8;
        T[tx][ty + i * 8] = s[(size_t)k * Nd + nt * 32 + tx];
    }
    __syncthreads();
#pragma unroll
    for (int i = 0; i < 4; i++) {
        int n = nt * 32 + ty + i * 8;
        dst[(size_t)n * Kd + kt * 32 + tx] = __float2bfloat16(T[ty + i * 8][tx]);
    }
}

// ---------------------------------------------------------------------------
// Deformable bilinear sampling (R8 version, 44.7 us best). Block = 8 queries,
// LDS 4B/entry, stride-65, 16-deep batched 16B gathers.
// ---------------------------------------------------------------------------
#define QB 8
__global__ __launch_bounds__(256, 4)
void sample_kernel(const float* __restrict__ refp, const float* __restrict__ offb,
                   const float* __restrict__ attn,
                   const __hip_bfloat16* __restrict__ value,
                   __hip_bfloat16* __restrict__ tgt2)
{
    __shared__ unsigned spk[64 * 65];       // [sc=lp*4+c][g=ql*8+h]

    const int q0  = blockIdx.x * QB;
    const int tid = threadIdx.x;

#pragma unroll
    for (int k = 0; k < 4; k++) {
        const int it = tid + k * 256;        // (ql,h,lp)
        const int ql = it >> 7, h = (it >> 4) & 7, lp = it & 15;
        const int l = lp >> 2, p = lp & 3;
        const int q = q0 + ql, b = q >> 13;
        const int Wl = 128 >> l;
        const int LST = (l == 0) ? 0 : (l == 1) ? 16384 : (l == 2) ? 20480 : 21504;

        const float rx = refp[((size_t)q * N_LEVELS + l) * 2 + 0];
        const float ry = refp[((size_t)q * N_LEVELS + l) * 2 + 1];
        const float ox = offb[(size_t)q * 256 + h * 32 + l * 8 + p * 2 + 0];
        const float oy = offb[(size_t)q * 256 + h * 32 + l * 8 + p * 2 + 1];
        const float a  = attn[(size_t)q * 128 + h * 16 + lp];

        const float x = rx * Wl - 0.5f + ox;
        const float y = ry * Wl - 0.5f + oy;
        const float x0f = floorf(x), y0f = floorf(y);
        const float wx = x - x0f, wy = y - y0f;
        const int ix = (int)x0f, iy = (int)y0f;
        const int base = b * S_TOTAL + LST;
        const int g = ql * 8 + h;
        const float cw[4] = {(1.f - wx) * (1.f - wy) * a, wx * (1.f - wy) * a,
                             (1.f - wx) * wy * a,         wx * wy * a};
#pragma unroll
        for (int c = 0; c < 4; c++) {
            const int xi = ix + (c & 1), yi = iy + (c >> 1);
            const bool valid = ((unsigned)xi < (unsigned)Wl) && ((unsigned)yi < (unsigned)Wl);
            const unsigned pix = valid ? (unsigned)(base + yi * Wl + xi) : (unsigned)base;
            const __half hw = __float2half(valid ? cw[c] : 0.f);
            spk[(lp * 4 + c) * 65 + g] = (pix << 16) | (unsigned)__half_as_ushort(hw);
        }
    }
    __syncthreads();

    const int ql = tid >> 5, h = (tid >> 2) & 7, d4 = tid & 3;
    const int q = q0 + ql, g = ql * 8 + h;
    const int c0 = h * 32 + d4 * 8;
    const char* vb = (const char*)value + (size_t)c0 * 2;

    float ac[8] = {0.f, 0.f, 0.f, 0.f, 0.f, 0.f, 0.f, 0.f};
#pragma unroll
    for (int ch = 0; ch < 4; ch++) {
        unsigned us[16];
#pragma unroll
        for (int j = 0; j < 16; j++) us[j] = spk[(ch * 16 + j) * 65 + g];
        uint4 rv[16];
#pragma unroll
        for (int j = 0; j < 16; j++)
            rv[j] = *(const uint4*)(vb + ((size_t)(us[j] >> 16) << 9));
#pragma unroll
        for (int j = 0; j < 16; j++) {
            float wv = __half2float(__ushort_as_half((unsigned short)(us[j] & 0xffffu)));
            ac[0] += wv * __uint_as_float(rv[j].x << 16);
            ac[1] += wv * __uint_as_float(rv[j].x & 0xffff0000u);
            ac[2] += wv * __uint_as_float(rv[j].y << 16);
            ac[3] += wv * __uint_as_float(rv[j].y & 0xffff0000u);
            ac[4] += wv * __uint_as_float(rv[j].z << 16);
            ac[5] += wv * __uint_as_float(rv[j].z & 0xffff0000u);
            ac[6] += wv * __uint_as_float(rv[j].w << 16);
            ac[7] += wv * __uint_as_float(rv[j].w & 0xffff0000u);
        }
    }
    bh8 o;
#pragma unroll
    for (int i = 0; i < 8; i++) o.v[i] = __float2bfloat16(ac[i]);
    *(bh8*)(tgt2 + (size_t)q * 256 + c0) = o;
}

// ---------------------------------------------------------------------------
extern "C" void kernel_launch(void* const* d_in, const int* in_sizes, int n_in,
                              void* d_out, int out_size, void* d_ws, size_t ws_size,
                              hipStream_t stream) {
    const float* tgt     = (const float*)d_in[0];
    const float* qpos    = (const float*)d_in[1];
    const float* refp    = (const float*)d_in[2];
    const float* src     = (const float*)d_in[3];
    const float* W_value = (const float*)d_in[6];
    const float* b_value = (const float*)d_in[7];
    const float* W_off   = (const float*)d_in[8];
    const float* b_off   = (const float*)d_in[9];
    const float* W_attn  = (const float*)d_in[10];
    const float* b_attn  = (const float*)d_in[11];
    const float* W_out   = (const float*)d_in[12];
    const float* b_out   = (const float*)d_in[13];
    const float* ln1_g   = (const float*)d_in[14];
    const float* ln1_b   = (const float*)d_in[15];
    const float* W1      = (const float*)d_in[16];
    const float* b1      = (const float*)d_in[17];
    const float* W2      = (const float*)d_in[18];
    const float* b2      = (const float*)d_in[19];
    const float* ln3_g   = (const float*)d_in[20];
    const float* ln3_b   = (const float*)d_in[21];
    float* out = (float*)d_out;

    // workspace layout
    char* p = (char*)d_ws;
    auto nxt = [&](size_t b) { char* r = p; p += (b + 255) & ~(size_t)255; return r; };
    __hip_bfloat16* Wvt    = (__hip_bfloat16*)nxt((size_t)256 * 256 * 2);
    __hip_bfloat16* Woat   = (__hip_bfloat16*)nxt((size_t)384 * 256 * 2);
    __hip_bfloat16* Woutt  = (__hip_bfloat16*)nxt((size_t)256 * 256 * 2);
    __hip_bfloat16* W1t    = (__hip_bfloat16*)nxt((size_t)1024 * 256 * 2);
    __hip_bfloat16* W2t    = (__hip_bfloat16*)nxt((size_t)256 * 1024 * 2);
    __hip_bfloat16* valueb = (__hip_bfloat16*)nxt((size_t)M_V * 256 * 2);  // dead after sampler
    float*          offb   = (float*)nxt((size_t)M_Q * 256 * 4);           // dead after sampler
    float*          attnb  = (float*)nxt((size_t)M_Q * 128 * 4);
    __hip_bfloat16* tgt2b  = (__hip_bfloat16*)nxt((size_t)M_Q * 256 * 2);
    __hip_bfloat16* t2ob   = (__hip_bfloat16*)nxt((size_t)M_Q * 256 * 2);
    float*          x      = (float*)nxt((size_t)M_Q * 256 * 4);
    __hip_bfloat16* xb     = (__hip_bfloat16*)nxt((size_t)M_Q * 256 * 2);  // SWIZZLED (ffn only)

    dim3 blk(256);

    // 0) prep: weight transpose+cvt only
    prep_kernel<<<dim3(736), blk, 0, stream>>>(
        W_value, W_off, W_attn, W_out, W1, W2,
        Wvt, Woat, Woat + 256 * 256, Woutt, W1t, W2t);

    // 1) value GEMM ++ off/attn GEMM (64x64, fused cvt, XCD swizzle)
    mfma_gemm_vq<<<dim3(VT64 * 4 + 256 / 8 * 48), blk, 0, stream>>>(
        src, Wvt, b_value, valueb, tgt, qpos, Woat, b_off, b_attn, offb, attnb);

    // 2) deformable sampling -> tgt2 (bf16)
    sample_kernel<<<dim3(M_Q / QB), blk, 0, stream>>>(refp, offb, attnb, valueb, tgt2b);

    // 3) t2o = tgt2 @ W_out + b_out -> bf16  (COLS=4, 1024 blocks)
    mfma_gemm64<256, 1, 4><<<dim3(M_Q / 64 * 4), blk, 0, stream>>>(
        tgt2b, Woutt, b_out, nullptr, t2ob, 256, 256, 256);

    // 4) x = LN1(tgt + t2o) -> f32 + swizzled bf16
    ln_kernel<true><<<dim3(M_Q / 4), blk, 0, stream>>>(
        nullptr, t2ob, nullptr, tgt, nullptr, ln1_g, ln1_b, x, xb);

    // 5+6+7) fused FFN + LN3: out = LN3(x + relu(xb@W1+b1)@W2 + b2)
    ffn_fused<<<dim3(M_Q / 32), dim3(512), 0, stream>>>(
        xb, W1t, b1, W2t, b2, x, ln3_g, ln3_b, out);
}

// Round 10
// 300.119 us; speedup vs baseline: 1.0542x; 1.0526x over previous
//
#include <hip/hip_runtime.h>
#include <hip/hip_bf16.h>
#include <hip/hip_fp16.h>
#include <math.h>

// Problem constants (fixed by setup_inputs)
#define D_MODEL   256
#define D_FFN     1024
#define N_LEVELS  4
#define N_HEADS   8
#define N_POINTS  4
#define BATCH     2
#define LQ        8192
#define S_TOTAL   21760            // 128*128 + 64*64 + 32*32 + 16*16
#define M_Q       (BATCH*LQ)       // 16384
#define M_V       (BATCH*S_TOTAL)  // 43520
#define VT64      (M_V/64)         // 680 row tiles for value GEMM

typedef __attribute__((ext_vector_type(8))) short bf16x8;   // 8 bf16 = 4 VGPRs
typedef __attribute__((ext_vector_type(4))) float floatx4;  // mfma C/D

struct alignas(8)  bh4 { __hip_bfloat16 a, b, c, d; };
struct alignas(16) bh8 { __hip_bfloat16 v[8]; };

__device__ __forceinline__ void gld_lds16(const void* g, void* l) {
    __builtin_amdgcn_global_load_lds(
        (const __attribute__((address_space(1))) void*)g,
        (__attribute__((address_space(3))) void*)l, 16, 0, 0);
}

__device__ __forceinline__ bh4 pack4(float4 a) {
    return { __float2bfloat16(a.x), __float2bfloat16(a.y),
             __float2bfloat16(a.z), __float2bfloat16(a.w) };
}

// ---------------------------------------------------------------------------
// 64x64 bf16 MFMA core, TRIPLE-buffered LDS, prefetch distance 2, counted
// vmcnt (R3 version, measured 294.75 us total). Session ledger:
//  - R1: 128^2 tile regressed (short-K: TLP > tile area)
//  - R7/R9: wave-private L2-direct FFN regressed (2 blk/CU can't hide L2 lat;
//    compiler sinks register prefetches, distance-2/3 was a no-op)
//  => massive block-TLP small-tile structure is the best measured here.
// ---------------------------------------------------------------------------
template<int K>
__device__ __forceinline__ void gemm_core64(const __hip_bfloat16* __restrict__ A,
                                            const __hip_bfloat16* __restrict__ Bt,
                                            int row0, int nb0, int lda, int ldb,
                                            short* As, short* Bs, floatx4 (&acc)[4])
{
    constexpr int NIT = K / 32;
    static_assert(NIT >= 2, "");
    const int tid  = threadIdx.x;
    const int w    = tid >> 6;
    const int lane = tid & 63;
    const int quad = lane >> 4;
    const int l15  = lane & 15;
    const size_t ldaB = (size_t)lda * 2, ldbB = (size_t)ldb * 2;

    const int o = w * 1024 + lane * 16;          // byte offset in 4KB tile
    const char* gA = (const char*)A + (size_t)(row0 + (o >> 6)) * ldaB + (o & 63);
    const char* gB = (const char*)Bt + (size_t)(nb0 + (o >> 6)) * ldbB + (o & 63);
    const int lofs = w * 512;                    // shorts

    gld_lds16(gA,      As + lofs);
    gld_lds16(gB,      Bs + lofs);
    gld_lds16(gA + 64, As + 2048 + lofs);
    gld_lds16(gB + 64, Bs + 2048 + lofs);

    int oc = 0, on = 2048, of = 4096;            // cur / next / far buffer offsets
#pragma unroll
    for (int it = 0; it < NIT; ++it) {
        if (it + 1 < NIT) asm volatile("s_waitcnt vmcnt(2)" ::: "memory");
        else              asm volatile("s_waitcnt vmcnt(0)" ::: "memory");
        __builtin_amdgcn_s_barrier();
        __builtin_amdgcn_sched_barrier(0);
        if (it + 2 < NIT) {
            const size_t kb = (size_t)(it + 2) * 64;   // 32 k * 2 B
            gld_lds16(gA + kb, As + of + lofs);
            gld_lds16(gB + kb, Bs + of + lofs);
        }
        const short* Ab = As + oc;
        const short* Bb = Bs + oc;
        bf16x8 af = *(const bf16x8*)&Ab[(w * 16 + l15) * 32 + quad * 8];
#pragma unroll
        for (int ni = 0; ni < 4; ni++) {
            bf16x8 bfr = *(const bf16x8*)&Bb[(ni * 16 + l15) * 32 + quad * 8];
            acc[ni] = __builtin_amdgcn_mfma_f32_16x16x32_bf16(af, bfr, acc[ni], 0, 0, 0);
        }
        int t = oc; oc = on; on = of; of = t;
    }
}

// ---------------------------------------------------------------------------
// 64x64 core with f32 A (optionally A+A2), cvt->bf16 during staging.
// ---------------------------------------------------------------------------
template<int K, bool ADD>
__device__ __forceinline__ void gemm_core_cvt64(const float* __restrict__ Af,
                                                const float* __restrict__ A2f,
                                                const __hip_bfloat16* __restrict__ Bt,
                                                int row0, int nb0, int lda, int ldb,
                                                short* As, short* Bs, floatx4 (&acc)[4])
{
    constexpr int NIT = K / 32;
    const int tid  = threadIdx.x;
    const int w    = tid >> 6;
    const int lane = tid & 63;
    const int quad = lane >> 4;
    const int l15  = lane & 15;

    const int o = w * 1024 + lane * 16;
    const char* gB = (const char*)Bt + (size_t)(nb0 + (o >> 6)) * ((size_t)ldb * 2) + (o & 63);
    const int lofs = w * 512;

    const int r0 = tid >> 3, k0 = (tid & 7) * 4;     // f32 index
    const float* gA0 = Af + (size_t)(row0 + r0) * lda + k0;        // rows 0..31
    const float* gA1 = gA0 + (size_t)32 * lda;                     // rows 32..63
    const float* gB0 = ADD ? (A2f + (size_t)(row0 + r0) * lda + k0) : nullptr;
    const float* gB1 = ADD ? (gB0 + (size_t)32 * lda) : nullptr;
    const int aofs0 = r0 * 32 + k0, aofs1 = aofs0 + 1024;

    float4 f0, f1;
    auto loadA = [&](int kt) {
        f0 = *(const float4*)(gA0 + kt);
        f1 = *(const float4*)(gA1 + kt);
        if (ADD) {
            float4 a = *(const float4*)(gB0 + kt);
            float4 b = *(const float4*)(gB1 + kt);
            f0.x += a.x; f0.y += a.y; f0.z += a.z; f0.w += a.w;
            f1.x += b.x; f1.y += b.y; f1.z += b.z; f1.w += b.w;
        }
    };
    auto writeA = [&](short* buf) {
        *(bh4*)&buf[aofs0] = pack4(f0);
        *(bh4*)&buf[aofs1] = pack4(f1);
    };

    loadA(0);
    gld_lds16(gB, Bs + lofs);
    writeA(As);

#pragma unroll 8
    for (int it = 0; it < NIT; ++it) {
        __syncthreads();
        const int cb = it & 1;
        const bool more = (it + 1 < NIT);
        if (more) {
            loadA((it + 1) * 32);
            gld_lds16(gB + (size_t)(it + 1) * 64, Bs + (cb ^ 1) * 2048 + lofs);
        }
        const short* Ab = As + cb * 2048;
        const short* Bb = Bs + cb * 2048;
        bf16x8 af = *(const bf16x8*)&Ab[(w * 16 + l15) * 32 + quad * 8];
#pragma unroll
        for (int ni = 0; ni < 4; ni++) {
            bf16x8 bfr = *(const bf16x8*)&Bb[(ni * 16 + l15) * 32 + quad * 8];
            acc[ni] = __builtin_amdgcn_mfma_f32_16x16x32_bf16(af, bfr, acc[ni], 0, 0, 0);
        }
        if (more) writeA(As + (cb ^ 1) * 2048);
    }
}

// ---------------------------------------------------------------------------
// Generic 64x64 GEMM, bf16 A. 1-D grid of rows*COLS blocks with XCD-aware
// swizzle: id = g*(8*COLS) + col*8 + rowlane, so the COLS blocks sharing an
// A row-tile all have id = rowlane (mod 8) -> SAME XCD -> A fetched from
// HBM once into that XCD's L2.
// EPI: 0 f32 (+bias); 1 bf16 (+bias); 2 relu -> bf16.
// ---------------------------------------------------------------------------
template<int K, int EPI, int COLS>
__global__ __launch_bounds__(256)
void mfma_gemm64(const __hip_bfloat16* __restrict__ A,
                 const __hip_bfloat16* __restrict__ Bt,
                 const float* __restrict__ bias,
                 float* __restrict__ outf, __hip_bfloat16* __restrict__ outb,
                 int lda, int ldb, int ldOut)
{
    __shared__ alignas(16) short As[3 * 2048];
    __shared__ alignas(16) short Bs[3 * 2048];

    constexpr int BPG = 8 * COLS;
    const int g  = blockIdx.x / BPG;
    const int wq = blockIdx.x % BPG;
    const int row0 = (g * 8 + (wq & 7)) * 64;
    const int nb0  = (wq >> 3) * 64;

    const int tid = threadIdx.x, w = tid >> 6, lane = tid & 63;
    const int quad = lane >> 4, l15 = lane & 15;

    floatx4 acc[4];
#pragma unroll
    for (int ni = 0; ni < 4; ni++) acc[ni] = (floatx4){0.f, 0.f, 0.f, 0.f};

    gemm_core64<K>(A, Bt, row0, nb0, lda, ldb, As, Bs, acc);

    float bias_c[4];
#pragma unroll
    for (int ni = 0; ni < 4; ni++) bias_c[ni] = bias ? bias[nb0 + ni * 16 + l15] : 0.f;

#pragma unroll
    for (int r = 0; r < 4; r++) {
        int row = row0 + w * 16 + quad * 4 + r;
        size_t rb = (size_t)row * ldOut + nb0;
#pragma unroll
        for (int ni = 0; ni < 4; ni++) {
            float v = acc[ni][r] + bias_c[ni];
            if (EPI == 2)      outb[rb + ni * 16 + l15] = __float2bfloat16(fmaxf(v, 0.f));
            else if (EPI == 1) outb[rb + ni * 16 + l15] = __float2bfloat16(v);
            else               outf[rb + ni * 16 + l15] = v;
        }
    }
}

// ---------------------------------------------------------------------------
// Merged value-projection + off/attn GEMM (64x64, fused f32 cvt staging),
// 1-D grid with the same XCD-aware swizzle.
// ids [0, 2720): value part — groups of 32 = 8 rows x 4 cols.
// ids [2720, 4256): off/attn — groups of 48 = 8 rows x 6 cols
//   (col<4 -> off cols c*64, f32 ld 256; col>=4 -> attn, softmax16, ld 128).
// ---------------------------------------------------------------------------
__global__ __launch_bounds__(256)
void mfma_gemm_vq(const float* __restrict__ src,
                  const __hip_bfloat16* __restrict__ Wvt,
                  const float* __restrict__ b_value,
                  __hip_bfloat16* __restrict__ valueb,
                  const float* __restrict__ tgt, const float* __restrict__ qpos,
                  const __hip_bfloat16* __restrict__ Woat,
                  const float* __restrict__ b_off, const float* __restrict__ b_attn,
                  float* __restrict__ offb, float* __restrict__ attnb)
{
    __shared__ alignas(16) short As[2 * 2048];
    __shared__ alignas(16) short Bs[2 * 2048];

    const int id = blockIdx.x;
    const int tid = threadIdx.x, w = tid >> 6, lane = tid & 63;
    const int quad = lane >> 4, l15 = lane & 15;

    floatx4 acc[4];
#pragma unroll
    for (int ni = 0; ni < 4; ni++) acc[ni] = (floatx4){0.f, 0.f, 0.f, 0.f};

    if (id < VT64 * 4) {     // value part
        const int g = id >> 5, wq = id & 31;
        const int row0 = (g * 8 + (wq & 7)) * 64;
        const int nb0  = (wq >> 3) * 64;
        gemm_core_cvt64<256, false>(src, nullptr, Wvt, row0, nb0, 256, 256, As, Bs, acc);
        float bias_c[4];
#pragma unroll
        for (int ni = 0; ni < 4; ni++) bias_c[ni] = b_value[nb0 + ni * 16 + l15];
#pragma unroll
        for (int r = 0; r < 4; r++) {
            int row = row0 + w * 16 + quad * 4 + r;
            size_t rb = (size_t)row * 256 + nb0;
#pragma unroll
            for (int ni = 0; ni < 4; ni++)
                valueb[rb + ni * 16 + l15] = __float2bfloat16(acc[ni][r] + bias_c[ni]);
        }
        return;
    }

    const int oid = id - VT64 * 4;
    const int g = oid / 48, wq = oid % 48;
    const int row0 = (g * 8 + (wq & 7)) * 64;
    const int c = wq >> 3;   // 0..5

    if (c < 4) {             // offsets: cols c*64 of Woat, f32 out ld 256
        const int nb0 = c * 64;
        gemm_core_cvt64<256, true>(tgt, qpos, Woat, row0, nb0, 256, 256, As, Bs, acc);
        float bias_c[4];
#pragma unroll
        for (int ni = 0; ni < 4; ni++) bias_c[ni] = b_off[nb0 + ni * 16 + l15];
#pragma unroll
        for (int r = 0; r < 4; r++) {
            int row = row0 + w * 16 + quad * 4 + r;
            size_t rb = (size_t)row * 256 + nb0;
#pragma unroll
            for (int ni = 0; ni < 4; ni++)
                offb[rb + ni * 16 + l15] = acc[ni][r] + bias_c[ni];
        }
    } else {                 // attn: Woat rows 256 + (c-4)*64; softmax16
        const int c0 = (c - 4) * 64;
        gemm_core_cvt64<256, true>(tgt, qpos, Woat, row0, 256 + c0, 256, 256, As, Bs, acc);
        float bias_c[4];
#pragma unroll
        for (int ni = 0; ni < 4; ni++) bias_c[ni] = b_attn[c0 + ni * 16 + l15];
#pragma unroll
        for (int r = 0; r < 4; r++) {
            int row = row0 + w * 16 + quad * 4 + r;
            size_t rb = (size_t)row * 128 + c0;
#pragma unroll
            for (int ni = 0; ni < 4; ni++) {
                float v = acc[ni][r] + bias_c[ni];
                float m = v;
#pragma unroll
                for (int msk = 1; msk <= 8; msk <<= 1) m = fmaxf(m, __shfl_xor(m, msk));
                float e = __expf(v - m);
                float ssum = e;
#pragma unroll
                for (int msk = 1; msk <= 8; msk <<= 1) ssum += __shfl_xor(ssum, msk);
                attnb[rb + ni * 16 + l15] = e / ssum;
            }
        }
    }
}

// ---------------------------------------------------------------------------
// Residual + LayerNorm, one wave per 256-col row.
// v = resid + in1 (+ in2) (+ bias). B1: in1 is bf16.
// ---------------------------------------------------------------------------
template<bool B1>
__global__ __launch_bounds__(256)
void ln_kernel(const float* __restrict__ in1f, const __hip_bfloat16* __restrict__ in1b,
               const float* __restrict__ in2,
               const float* __restrict__ resid, const float* __restrict__ bias,
               const float* __restrict__ g, const float* __restrict__ b,
               float* __restrict__ outf, __hip_bfloat16* __restrict__ outb)
{
    const int row  = blockIdx.x * 4 + (threadIdx.x >> 6);
    const int lane = threadIdx.x & 63;
    const size_t rb = (size_t)row * 256 + lane * 4;

    float4 v = *(const float4*)(resid + rb);
    if (B1) {
        bh4 a = *(const bh4*)(in1b + rb);
        v.x += __bfloat162float(a.a); v.y += __bfloat162float(a.b);
        v.z += __bfloat162float(a.c); v.w += __bfloat162float(a.d);
    } else {
        float4 a = *(const float4*)(in1f + rb);
        v.x += a.x; v.y += a.y; v.z += a.z; v.w += a.w;
    }
    if (in2) {
        float4 c = *(const float4*)(in2 + rb);
        v.x += c.x; v.y += c.y; v.z += c.z; v.w += c.w;
    }
    if (bias) {
        float4 c = *(const float4*)(bias + lane * 4);
        v.x += c.x; v.y += c.y; v.z += c.z; v.w += c.w;
    }
    float s  = v.x + v.y + v.z + v.w;
    float sq = v.x * v.x + v.y * v.y + v.z * v.z + v.w * v.w;
#pragma unroll
    for (int msk = 1; msk <= 32; msk <<= 1) {
        s += __shfl_xor(s, msk); sq += __shfl_xor(sq, msk);
    }
    float mean = s * (1.f / 256.f);
    float var  = sq * (1.f / 256.f) - mean * mean;
    float rstd = rsqrtf(var + 1e-5f);
    float4 gg = *(const float4*)(g + lane * 4);
    float4 bb = *(const float4*)(b + lane * 4);
    float4 o;
    o.x = (v.x - mean) * rstd * gg.x + bb.x;
    o.y = (v.y - mean) * rstd * gg.y + bb.y;
    o.z = (v.z - mean) * rstd * gg.z + bb.z;
    o.w = (v.w - mean) * rstd * gg.w + bb.w;
    *(float4*)(outf + rb) = o;
    if (outb)
        *(bh4*)(outb + rb) = { __float2bfloat16(o.x), __float2bfloat16(o.y),
                               __float2bfloat16(o.z), __float2bfloat16(o.w) };
}

// ---------------------------------------------------------------------------
// Prep: weight transpose + f32->bf16 only (736 tiles of 32x32)
// ---------------------------------------------------------------------------
__global__ __launch_bounds__(256)
void prep_kernel(const float* w0, const float* w1, const float* w2,
                 const float* w3, const float* w4, const float* w5,
                 __hip_bfloat16* o0, __hip_bfloat16* o1, __hip_bfloat16* o2,
                 __hip_bfloat16* o3, __hip_bfloat16* o4, __hip_bfloat16* o5)
{
    int t = blockIdx.x;
    const float* s; __hip_bfloat16* dst; int Kd, Nd, tl;
    if      (t < 64)  { s = w0; dst = o0; Kd = 256;  Nd = 256;  tl = t; }
    else if (t < 128) { s = w1; dst = o1; Kd = 256;  Nd = 256;  tl = t - 64; }
    else if (t < 160) { s = w2; dst = o2; Kd = 256;  Nd = 128;  tl = t - 128; }
    else if (t < 224) { s = w3; dst = o3; Kd = 256;  Nd = 256;  tl = t - 160; }
    else if (t < 480) { s = w4; dst = o4; Kd = 256;  Nd = 1024; tl = t - 224; }
    else              { s = w5; dst = o5; Kd = 1024; Nd = 256;  tl = t - 480; }
    int ntn = Nd >> 5;
    int kt = tl / ntn, nt = tl - kt * ntn;
    __shared__ float T[32][33];
    int tx = threadIdx.x & 31, ty = threadIdx.x >> 5;
#pragma unroll
    for (int i = 0; i < 4; i++) {
        int k = kt * 32 + ty + i * 8;
        T[tx][ty + i * 8] = s[(size_t)k * Nd + nt * 32 + tx];
    }
    __syncthreads();
#pragma unroll
    for (int i = 0; i < 4; i++) {
        int n = nt * 32 + ty + i * 8;
        dst[(size_t)n * Kd + kt * 32 + tx] = __float2bfloat16(T[ty + i * 8][tx]);
    }
}

// ---------------------------------------------------------------------------
// Deformable bilinear sampling (R8 version, 44.7 us best). Block = 8 queries,
// LDS 4B/entry, stride-65, 16-deep batched 16B gathers.
// ---------------------------------------------------------------------------
#define QB 8
__global__ __launch_bounds__(256, 4)
void sample_kernel(const float* __restrict__ refp, const float* __restrict__ offb,
                   const float* __restrict__ attn,
                   const __hip_bfloat16* __restrict__ value,
                   __hip_bfloat16* __restrict__ tgt2)
{
    __shared__ unsigned spk[64 * 65];       // [sc=lp*4+c][g=ql*8+h]

    const int q0  = blockIdx.x * QB;
    const int tid = threadIdx.x;

#pragma unroll
    for (int k = 0; k < 4; k++) {
        const int it = tid + k * 256;        // (ql,h,lp)
        const int ql = it >> 7, h = (it >> 4) & 7, lp = it & 15;
        const int l = lp >> 2, p = lp & 3;
        const int q = q0 + ql, b = q >> 13;
        const int Wl = 128 >> l;
        const int LST = (l == 0) ? 0 : (l == 1) ? 16384 : (l == 2) ? 20480 : 21504;

        const float rx = refp[((size_t)q * N_LEVELS + l) * 2 + 0];
        const float ry = refp[((size_t)q * N_LEVELS + l) * 2 + 1];
        const float ox = offb[(size_t)q * 256 + h * 32 + l * 8 + p * 2 + 0];
        const float oy = offb[(size_t)q * 256 + h * 32 + l * 8 + p * 2 + 1];
        const float a  = attn[(size_t)q * 128 + h * 16 + lp];

        const float x = rx * Wl - 0.5f + ox;
        const float y = ry * Wl - 0.5f + oy;
        const float x0f = floorf(x), y0f = floorf(y);
        const float wx = x - x0f, wy = y - y0f;
        const int ix = (int)x0f, iy = (int)y0f;
        const int base = b * S_TOTAL + LST;
        const int g = ql * 8 + h;
        const float cw[4] = {(1.f - wx) * (1.f - wy) * a, wx * (1.f - wy) * a,
                             (1.f - wx) * wy * a,         wx * wy * a};
#pragma unroll
        for (int c = 0; c < 4; c++) {
            const int xi = ix + (c & 1), yi = iy + (c >> 1);
            const bool valid = ((unsigned)xi < (unsigned)Wl) && ((unsigned)yi < (unsigned)Wl);
            const unsigned pix = valid ? (unsigned)(base + yi * Wl + xi) : (unsigned)base;
            const __half hw = __float2half(valid ? cw[c] : 0.f);
            spk[(lp * 4 + c) * 65 + g] = (pix << 16) | (unsigned)__half_as_ushort(hw);
        }
    }
    __syncthreads();

    const int ql = tid >> 5, h = (tid >> 2) & 7, d4 = tid & 3;
    const int q = q0 + ql, g = ql * 8 + h;
    const int c0 = h * 32 + d4 * 8;
    const char* vb = (const char*)value + (size_t)c0 * 2;

    float ac[8] = {0.f, 0.f, 0.f, 0.f, 0.f, 0.f, 0.f, 0.f};
#pragma unroll
    for (int ch = 0; ch < 4; ch++) {
        unsigned us[16];
#pragma unroll
        for (int j = 0; j < 16; j++) us[j] = spk[(ch * 16 + j) * 65 + g];
        uint4 rv[16];
#pragma unroll
        for (int j = 0; j < 16; j++)
            rv[j] = *(const uint4*)(vb + ((size_t)(us[j] >> 16) << 9));
#pragma unroll
        for (int j = 0; j < 16; j++) {
            float wv = __half2float(__ushort_as_half((unsigned short)(us[j] & 0xffffu)));
            ac[0] += wv * __uint_as_float(rv[j].x << 16);
            ac[1] += wv * __uint_as_float(rv[j].x & 0xffff0000u);
            ac[2] += wv * __uint_as_float(rv[j].y << 16);
            ac[3] += wv * __uint_as_float(rv[j].y & 0xffff0000u);
            ac[4] += wv * __uint_as_float(rv[j].z << 16);
            ac[5] += wv * __uint_as_float(rv[j].z & 0xffff0000u);
            ac[6] += wv * __uint_as_float(rv[j].w << 16);
            ac[7] += wv * __uint_as_float(rv[j].w & 0xffff0000u);
        }
    }
    bh8 o;
#pragma unroll
    for (int i = 0; i < 8; i++) o.v[i] = __float2bfloat16(ac[i]);
    *(bh8*)(tgt2 + (size_t)q * 256 + c0) = o;
}

// ---------------------------------------------------------------------------
extern "C" void kernel_launch(void* const* d_in, const int* in_sizes, int n_in,
                              void* d_out, int out_size, void* d_ws, size_t ws_size,
                              hipStream_t stream) {
    const float* tgt     = (const float*)d_in[0];
    const float* qpos    = (const float*)d_in[1];
    const float* refp    = (const float*)d_in[2];
    const float* src     = (const float*)d_in[3];
    const float* W_value = (const float*)d_in[6];
    const float* b_value = (const float*)d_in[7];
    const float* W_off   = (const float*)d_in[8];
    const float* b_off   = (const float*)d_in[9];
    const float* W_attn  = (const float*)d_in[10];
    const float* b_attn  = (const float*)d_in[11];
    const float* W_out   = (const float*)d_in[12];
    const float* b_out   = (const float*)d_in[13];
    const float* ln1_g   = (const float*)d_in[14];
    const float* ln1_b   = (const float*)d_in[15];
    const float* W1      = (const float*)d_in[16];
    const float* b1      = (const float*)d_in[17];
    const float* W2      = (const float*)d_in[18];
    const float* b2      = (const float*)d_in[19];
    const float* ln3_g   = (const float*)d_in[20];
    const float* ln3_b   = (const float*)d_in[21];
    float* out = (float*)d_out;

    // workspace layout
    char* p = (char*)d_ws;
    auto nxt = [&](size_t b) { char* r = p; p += (b + 255) & ~(size_t)255; return r; };
    __hip_bfloat16* Wvt    = (__hip_bfloat16*)nxt((size_t)256 * 256 * 2);
    __hip_bfloat16* Woat   = (__hip_bfloat16*)nxt((size_t)384 * 256 * 2);
    __hip_bfloat16* Woutt  = (__hip_bfloat16*)nxt((size_t)256 * 256 * 2);
    __hip_bfloat16* W1t    = (__hip_bfloat16*)nxt((size_t)1024 * 256 * 2);
    __hip_bfloat16* W2t    = (__hip_bfloat16*)nxt((size_t)256 * 1024 * 2);
    __hip_bfloat16* valueb = (__hip_bfloat16*)nxt((size_t)M_V * 256 * 2);  // dead after sampler
    float*          offb   = (float*)nxt((size_t)M_Q * 256 * 4);           // dead after sampler
    float*          attnb  = (float*)nxt((size_t)M_Q * 128 * 4);
    __hip_bfloat16* tgt2b  = (__hip_bfloat16*)nxt((size_t)M_Q * 256 * 2);
    __hip_bfloat16* t2ob   = (__hip_bfloat16*)nxt((size_t)M_Q * 256 * 2);
    float*          x      = (float*)nxt((size_t)M_Q * 256 * 4);
    __hip_bfloat16* xb     = (__hip_bfloat16*)nxt((size_t)M_Q * 256 * 2);
    __hip_bfloat16* hb     = (__hip_bfloat16*)nxt((size_t)M_Q * 1024 * 2);
    // FFN2 output (f32, 16.8 MB) overlays valueb (dead after sampler)
    float* f2o = (float*)valueb;

    dim3 blk(256);

    // 0) prep: weight transpose+cvt only
    prep_kernel<<<dim3(736), blk, 0, stream>>>(
        W_value, W_off, W_attn, W_out, W1, W2,
        Wvt, Woat, Woat + 256 * 256, Woutt, W1t, W2t);

    // 1) value GEMM ++ off/attn GEMM (64x64, fused cvt, XCD swizzle)
    mfma_gemm_vq<<<dim3(VT64 * 4 + 256 / 8 * 48), blk, 0, stream>>>(
        src, Wvt, b_value, valueb, tgt, qpos, Woat, b_off, b_attn, offb, attnb);

    // 2) deformable sampling -> tgt2 (bf16)
    sample_kernel<<<dim3(M_Q / QB), blk, 0, stream>>>(refp, offb, attnb, valueb, tgt2b);

    // 3) t2o = tgt2 @ W_out + b_out -> bf16  (COLS=4, 1024 blocks)
    mfma_gemm64<256, 1, 4><<<dim3(M_Q / 64 * 4), blk, 0, stream>>>(
        tgt2b, Woutt, b_out, nullptr, t2ob, 256, 256, 256);

    // 4) x = LN1(tgt + t2o) -> f32 + bf16
    ln_kernel<true><<<dim3(M_Q / 4), blk, 0, stream>>>(
        nullptr, t2ob, nullptr, tgt, nullptr, ln1_g, ln1_b, x, xb);

    // 5) h = relu(x @ W1 + b1) -> bf16  (COLS=16, 4096 blocks)
    mfma_gemm64<256, 2, 16><<<dim3(M_Q / 64 * 16), blk, 0, stream>>>(
        xb, W1t, b1, nullptr, hb, 256, 256, 1024);

    // 6) f2o = h @ W2 + b2 -> f32, K=1024  (COLS=4, 1024 blocks)
    mfma_gemm64<1024, 0, 4><<<dim3(M_Q / 64 * 4), blk, 0, stream>>>(
        hb, W2t, b2, f2o, nullptr, 1024, 1024, 256);

    // 7) out = LN3(x + f2o) -> f32
    ln_kernel<false><<<dim3(M_Q / 4), blk, 0, stream>>>(
        f2o, nullptr, nullptr, x, nullptr, ln3_g, ln3_b, out, nullptr);
}

// Round 13
// 288.292 us; speedup vs baseline: 1.0974x; 1.0410x over previous
//
#include <hip/hip_runtime.h>
#include <hip/hip_bf16.h>
#include <hip/hip_fp16.h>
#include <math.h>

// Problem constants (fixed by setup_inputs)
#define D_MODEL   256
#define D_FFN     1024
#define N_LEVELS  4
#define N_HEADS   8
#define N_POINTS  4
#define BATCH     2
#define LQ        8192
#define S_TOTAL   21760            // 128*128 + 64*64 + 32*32 + 16*16
#define M_Q       (BATCH*LQ)       // 16384
#define M_V       (BATCH*S_TOTAL)  // 43520
#define VT64      (M_V/64)         // 680 row tiles for value GEMM

typedef __attribute__((ext_vector_type(8))) short bf16x8;   // 8 bf16 = 4 VGPRs
typedef __attribute__((ext_vector_type(4))) float floatx4;  // mfma C/D

struct alignas(8)  bh4 { __hip_bfloat16 a, b, c, d; };
struct alignas(16) bh8 { __hip_bfloat16 v[8]; };

__device__ __forceinline__ void gld_lds16(const void* g, void* l) {
    __builtin_amdgcn_global_load_lds(
        (const __attribute__((address_space(1))) void*)g,
        (__attribute__((address_space(3))) void*)l, 16, 0, 0);
}

__device__ __forceinline__ bh4 pack4(float4 a) {
    return { __float2bfloat16(a.x), __float2bfloat16(a.y),
             __float2bfloat16(a.z), __float2bfloat16(a.w) };
}

// ---------------------------------------------------------------------------
// 64x64 bf16 MFMA core, TRIPLE-buffered LDS, prefetch distance 2, counted
// vmcnt (R3 version, best measured total 294.75 us). Session ledger:
//  - R1: 128^2 tile regressed (short-K: TLP > tile area)
//  - R7/R9: wave-private L2-direct FFN regressed; compiler sinks register
//    prefetches (distance-2/3 was a no-op at VGPR 64)
//  - R10: revert re-measured 300.1 (noise band +-3-5 us vs 294.75)
// ---------------------------------------------------------------------------
template<int K>
__device__ __forceinline__ void gemm_core64(const __hip_bfloat16* __restrict__ A,
                                            const __hip_bfloat16* __restrict__ Bt,
                                            int row0, int nb0, int lda, int ldb,
                                            short* As, short* Bs, floatx4 (&acc)[4])
{
    constexpr int NIT = K / 32;
    static_assert(NIT >= 2, "");
    const int tid  = threadIdx.x;
    const int w    = tid >> 6;
    const int lane = tid & 63;
    const int quad = lane >> 4;
    const int l15  = lane & 15;
    const size_t ldaB = (size_t)lda * 2, ldbB = (size_t)ldb * 2;

    const int o = w * 1024 + lane * 16;          // byte offset in 4KB tile
    const char* gA = (const char*)A + (size_t)(row0 + (o >> 6)) * ldaB + (o & 63);
    const char* gB = (const char*)Bt + (size_t)(nb0 + (o >> 6)) * ldbB + (o & 63);
    const int lofs = w * 512;                    // shorts

    gld_lds16(gA,      As + lofs);
    gld_lds16(gB,      Bs + lofs);
    gld_lds16(gA + 64, As + 2048 + lofs);
    gld_lds16(gB + 64, Bs + 2048 + lofs);

    int oc = 0, on = 2048, of = 4096;            // cur / next / far buffer offsets
#pragma unroll
    for (int it = 0; it < NIT; ++it) {
        if (it + 1 < NIT) asm volatile("s_waitcnt vmcnt(2)" ::: "memory");
        else              asm volatile("s_waitcnt vmcnt(0)" ::: "memory");
        __builtin_amdgcn_s_barrier();
        __builtin_amdgcn_sched_barrier(0);
        if (it + 2 < NIT) {
            const size_t kb = (size_t)(it + 2) * 64;   // 32 k * 2 B
            gld_lds16(gA + kb, As + of + lofs);
            gld_lds16(gB + kb, Bs + of + lofs);
        }
        const short* Ab = As + oc;
        const short* Bb = Bs + oc;
        bf16x8 af = *(const bf16x8*)&Ab[(w * 16 + l15) * 32 + quad * 8];
#pragma unroll
        for (int ni = 0; ni < 4; ni++) {
            bf16x8 bfr = *(const bf16x8*)&Bb[(ni * 16 + l15) * 32 + quad * 8];
            acc[ni] = __builtin_amdgcn_mfma_f32_16x16x32_bf16(af, bfr, acc[ni], 0, 0, 0);
        }
        int t = oc; oc = on; on = of; of = t;
    }
}

// ---------------------------------------------------------------------------
// 64x64 core with f32 A (optionally A+A2), cvt->bf16 during staging.
// R11: BK=64 — TWO 32-k tiles per barrier (4 barriers for K=256 instead of
// 8). Top-down showed ~3k wall-cycles/iter vs ~600-cy critical path at the
// old BK=32: barrier skew+drain dominated. Doubling work per barrier halves
// that overhead and doubles every load->use window. LDS 16->32 KB (5 blk/CU
// cap > measured 2.8 residency); VGPR ~80 (4 waves/SIMD cap > measured 2.8).
// ---------------------------------------------------------------------------
template<int K, bool ADD>
__device__ __forceinline__ void gemm_core_cvt64(const float* __restrict__ Af,
                                                const float* __restrict__ A2f,
                                                const __hip_bfloat16* __restrict__ Bt,
                                                int row0, int nb0, int lda, int ldb,
                                                short* As, short* Bs, floatx4 (&acc)[4])
{
    constexpr int NST = K / 64;                  // stages of 64 k
    static_assert(K % 64 == 0 && NST >= 2, "");
    const int tid  = threadIdx.x;
    const int w    = tid >> 6;
    const int lane = tid & 63;
    const int quad = lane >> 4;
    const int l15  = lane & 15;

    const int o = w * 1024 + lane * 16;          // byte offset in 4KB B tile
    const char* gB = (const char*)Bt + (size_t)(nb0 + (o >> 6)) * ((size_t)ldb * 2) + (o & 63);
    const int lofs = w * 512;                    // shorts

    const int r0 = tid >> 3, k0 = (tid & 7) * 4;     // f32 index
    const float* gA0 = Af + (size_t)(row0 + r0) * lda + k0;        // rows 0..31
    const float* gA1 = gA0 + (size_t)32 * lda;                     // rows 32..63
    const float* gB0 = ADD ? (A2f + (size_t)(row0 + r0) * lda + k0) : nullptr;
    const float* gB1 = ADD ? (gB0 + (size_t)32 * lda) : nullptr;
    const int aofs0 = r0 * 32 + k0, aofs1 = aofs0 + 1024;

    float4 f[4];                                 // [t0r0, t0r1, t1r0, t1r1]
    auto loadA2 = [&](int kt) {                  // two 32-k tiles at kt, kt+32
        f[0] = *(const float4*)(gA0 + kt);
        f[1] = *(const float4*)(gA1 + kt);
        f[2] = *(const float4*)(gA0 + kt + 32);
        f[3] = *(const float4*)(gA1 + kt + 32);
        if (ADD) {
            float4 a0 = *(const float4*)(gB0 + kt);
            float4 a1 = *(const float4*)(gB1 + kt);
            float4 a2 = *(const float4*)(gB0 + kt + 32);
            float4 a3 = *(const float4*)(gB1 + kt + 32);
            f[0].x += a0.x; f[0].y += a0.y; f[0].z += a0.z; f[0].w += a0.w;
            f[1].x += a1.x; f[1].y += a1.y; f[1].z += a1.z; f[1].w += a1.w;
            f[2].x += a2.x; f[2].y += a2.y; f[2].z += a2.z; f[2].w += a2.w;
            f[3].x += a3.x; f[3].y += a3.y; f[3].z += a3.z; f[3].w += a3.w;
        }
    };
    auto writeA2 = [&](short* buf) {             // buf = 4096-short stage base
        *(bh4*)&buf[aofs0]        = pack4(f[0]);
        *(bh4*)&buf[aofs1]        = pack4(f[1]);
        *(bh4*)&buf[aofs0 + 2048] = pack4(f[2]);
        *(bh4*)&buf[aofs1 + 2048] = pack4(f[3]);
    };
    auto stageB = [&](int s, short* buf) {       // two gld_lds per stage
        gld_lds16(gB + (size_t)(2 * s)     * 64, buf + lofs);
        gld_lds16(gB + (size_t)(2 * s + 1) * 64, buf + 2048 + lofs);
    };

    loadA2(0);
    stageB(0, Bs);
    writeA2(As);

#pragma unroll
    for (int s = 0; s < NST; ++s) {
        __syncthreads();
        const int cb = s & 1;
        const bool more = (s + 1 < NST);
        if (more) {
            loadA2((s + 1) * 64);
            stageB(s + 1, Bs + (cb ^ 1) * 4096);
        }
        const short* Ab = As + cb * 4096;
        const short* Bb = Bs + cb * 4096;
#pragma unroll
        for (int sub = 0; sub < 2; sub++) {
            bf16x8 af = *(const bf16x8*)&Ab[sub * 2048 + (w * 16 + l15) * 32 + quad * 8];
#pragma unroll
            for (int ni = 0; ni < 4; ni++) {
                bf16x8 bfr = *(const bf16x8*)&Bb[sub * 2048 + (ni * 16 + l15) * 32 + quad * 8];
                acc[ni] = __builtin_amdgcn_mfma_f32_16x16x32_bf16(af, bfr, acc[ni], 0, 0, 0);
            }
        }
        if (more) writeA2(As + (cb ^ 1) * 4096);
    }
}

// ---------------------------------------------------------------------------
// Generic 64x64 GEMM, bf16 A. 1-D grid of rows*COLS blocks with XCD-aware
// swizzle: id = g*(8*COLS) + col*8 + rowlane, so the COLS blocks sharing an
// A row-tile all have id = rowlane (mod 8) -> SAME XCD -> A fetched from
// HBM once into that XCD's L2.
// EPI: 0 f32 (+bias); 1 bf16 (+bias); 2 relu -> bf16.
// ---------------------------------------------------------------------------
template<int K, int EPI, int COLS>
__global__ __launch_bounds__(256)
void mfma_gemm64(const __hip_bfloat16* __restrict__ A,
                 const __hip_bfloat16* __restrict__ Bt,
                 const float* __restrict__ bias,
                 float* __restrict__ outf, __hip_bfloat16* __restrict__ outb,
                 int lda, int ldb, int ldOut)
{
    __shared__ alignas(16) short As[3 * 2048];
    __shared__ alignas(16) short Bs[3 * 2048];

    constexpr int BPG = 8 * COLS;
    const int g  = blockIdx.x / BPG;
    const int wq = blockIdx.x % BPG;
    const int row0 = (g * 8 + (wq & 7)) * 64;
    const int nb0  = (wq >> 3) * 64;

    const int tid = threadIdx.x, w = tid >> 6, lane = tid & 63;
    const int quad = lane >> 4, l15 = lane & 15;

    floatx4 acc[4];
#pragma unroll
    for (int ni = 0; ni < 4; ni++) acc[ni] = (floatx4){0.f, 0.f, 0.f, 0.f};

    gemm_core64<K>(A, Bt, row0, nb0, lda, ldb, As, Bs, acc);

    float bias_c[4];
#pragma unroll
    for (int ni = 0; ni < 4; ni++) bias_c[ni] = bias ? bias[nb0 + ni * 16 + l15] : 0.f;

#pragma unroll
    for (int r = 0; r < 4; r++) {
        int row = row0 + w * 16 + quad * 4 + r;
        size_t rb = (size_t)row * ldOut + nb0;
#pragma unroll
        for (int ni = 0; ni < 4; ni++) {
            float v = acc[ni][r] + bias_c[ni];
            if (EPI == 2)      outb[rb + ni * 16 + l15] = __float2bfloat16(fmaxf(v, 0.f));
            else if (EPI == 1) outb[rb + ni * 16 + l15] = __float2bfloat16(v);
            else               outf[rb + ni * 16 + l15] = v;
        }
    }
}

// ---------------------------------------------------------------------------
// Merged value-projection + off/attn GEMM (64x64, fused f32 cvt staging,
// BK=64 cvt core), 1-D grid with the same XCD-aware swizzle.
// ids [0, 2720): value part — groups of 32 = 8 rows x 4 cols.
// ids [2720, 4256): off/attn — groups of 48 = 8 rows x 6 cols
//   (col<4 -> off cols c*64, f32 ld 256; col>=4 -> attn, softmax16, ld 128).
// ---------------------------------------------------------------------------
__global__ __launch_bounds__(256)
void mfma_gemm_vq(const float* __restrict__ src,
                  const __hip_bfloat16* __restrict__ Wvt,
                  const float* __restrict__ b_value,
                  __hip_bfloat16* __restrict__ valueb,
                  const float* __restrict__ tgt, const float* __restrict__ qpos,
                  const __hip_bfloat16* __restrict__ Woat,
                  const float* __restrict__ b_off, const float* __restrict__ b_attn,
                  float* __restrict__ offb, float* __restrict__ attnb)
{
    __shared__ alignas(16) short As[2 * 4096];
    __shared__ alignas(16) short Bs[2 * 4096];

    const int id = blockIdx.x;
    const int tid = threadIdx.x, w = tid >> 6, lane = tid & 63;
    const int quad = lane >> 4, l15 = lane & 15;

    floatx4 acc[4];
#pragma unroll
    for (int ni = 0; ni < 4; ni++) acc[ni] = (floatx4){0.f, 0.f, 0.f, 0.f};

    if (id < VT64 * 4) {     // value part
        const int g = id >> 5, wq = id & 31;
        const int row0 = (g * 8 + (wq & 7)) * 64;
        const int nb0  = (wq >> 3) * 64;
        gemm_core_cvt64<256, false>(src, nullptr, Wvt, row0, nb0, 256, 256, As, Bs, acc);
        float bias_c[4];
#pragma unroll
        for (int ni = 0; ni < 4; ni++) bias_c[ni] = b_value[nb0 + ni * 16 + l15];
#pragma unroll
        for (int r = 0; r < 4; r++) {
            int row = row0 + w * 16 + quad * 4 + r;
            size_t rb = (size_t)row * 256 + nb0;
#pragma unroll
            for (int ni = 0; ni < 4; ni++)
                valueb[rb + ni * 16 + l15] = __float2bfloat16(acc[ni][r] + bias_c[ni]);
        }
        return;
    }

    const int oid = id - VT64 * 4;
    const int g = oid / 48, wq = oid % 48;
    const int row0 = (g * 8 + (wq & 7)) * 64;
    const int c = wq >> 3;   // 0..5

    if (c < 4) {             // offsets: cols c*64 of Woat, f32 out ld 256
        const int nb0 = c * 64;
        gemm_core_cvt64<256, true>(tgt, qpos, Woat, row0, nb0, 256, 256, As, Bs, acc);
        float bias_c[4];
#pragma unroll
        for (int ni = 0; ni < 4; ni++) bias_c[ni] = b_off[nb0 + ni * 16 + l15];
#pragma unroll
        for (int r = 0; r < 4; r++) {
            int row = row0 + w * 16 + quad * 4 + r;
            size_t rb = (size_t)row * 256 + nb0;
#pragma unroll
            for (int ni = 0; ni < 4; ni++)
                offb[rb + ni * 16 + l15] = acc[ni][r] + bias_c[ni];
        }
    } else {                 // attn: Woat rows 256 + (c-4)*64; softmax16
        const int c0 = (c - 4) * 64;
        gemm_core_cvt64<256, true>(tgt, qpos, Woat, row0, 256 + c0, 256, 256, As, Bs, acc);
        float bias_c[4];
#pragma unroll
        for (int ni = 0; ni < 4; ni++) bias_c[ni] = b_attn[c0 + ni * 16 + l15];
#pragma unroll
        for (int r = 0; r < 4; r++) {
            int row = row0 + w * 16 + quad * 4 + r;
            size_t rb = (size_t)row * 128 + c0;
#pragma unroll
            for (int ni = 0; ni < 4; ni++) {
                float v = acc[ni][r] + bias_c[ni];
                float m = v;
#pragma unroll
                for (int msk = 1; msk <= 8; msk <<= 1) m = fmaxf(m, __shfl_xor(m, msk));
                float e = __expf(v - m);
                float ssum = e;
#pragma unroll
                for (int msk = 1; msk <= 8; msk <<= 1) ssum += __shfl_xor(ssum, msk);
                attnb[rb + ni * 16 + l15] = e / ssum;
            }
        }
    }
}

// ---------------------------------------------------------------------------
// Residual + LayerNorm, one wave per 256-col row.
// v = resid + in1 (+ in2) (+ bias). B1: in1 is bf16.
// ---------------------------------------------------------------------------
template<bool B1>
__global__ __launch_bounds__(256)
void ln_kernel(const float* __restrict__ in1f, const __hip_bfloat16* __restrict__ in1b,
               const float* __restrict__ in2,
               const float* __restrict__ resid, const float* __restrict__ bias,
               const float* __restrict__ g, const float* __restrict__ b,
               float* __restrict__ outf, __hip_bfloat16* __restrict__ outb)
{
    const int row  = blockIdx.x * 4 + (threadIdx.x >> 6);
    const int lane = threadIdx.x & 63;
    const size_t rb = (size_t)row * 256 + lane * 4;

    float4 v = *(const float4*)(resid + rb);
    if (B1) {
        bh4 a = *(const bh4*)(in1b + rb);
        v.x += __bfloat162float(a.a); v.y += __bfloat162float(a.b);
        v.z += __bfloat162float(a.c); v.w += __bfloat162float(a.d);
    } else {
        float4 a = *(const float4*)(in1f + rb);
        v.x += a.x; v.y += a.y; v.z += a.z; v.w += a.w;
    }
    if (in2) {
        float4 c = *(const float4*)(in2 + rb);
        v.x += c.x; v.y += c.y; v.z += c.z; v.w += c.w;
    }
    if (bias) {
        float4 c = *(const float4*)(bias + lane * 4);
        v.x += c.x; v.y += c.y; v.z += c.z; v.w += c.w;
    }
    float s  = v.x + v.y + v.z + v.w;
    float sq = v.x * v.x + v.y * v.y + v.z * v.z + v.w * v.w;
#pragma unroll
    for (int msk = 1; msk <= 32; msk <<= 1) {
        s += __shfl_xor(s, msk); sq += __shfl_xor(sq, msk);
    }
    float mean = s * (1.f / 256.f);
    float var  = sq * (1.f / 256.f) - mean * mean;
    float rstd = rsqrtf(var + 1e-5f);
    float4 gg = *(const float4*)(g + lane * 4);
    float4 bb = *(const float4*)(b + lane * 4);
    float4 o;
    o.x = (v.x - mean) * rstd * gg.x + bb.x;
    o.y = (v.y - mean) * rstd * gg.y + bb.y;
    o.z = (v.z - mean) * rstd * gg.z + bb.z;
    o.w = (v.w - mean) * rstd * gg.w + bb.w;
    *(float4*)(outf + rb) = o;
    if (outb)
        *(bh4*)(outb + rb) = { __float2bfloat16(o.x), __float2bfloat16(o.y),
                               __float2bfloat16(o.z), __float2bfloat16(o.w) };
}

// ---------------------------------------------------------------------------
// Prep: weight transpose + f32->bf16 only (736 tiles of 32x32)
// ---------------------------------------------------------------------------
__global__ __launch_bounds__(256)
void prep_kernel(const float* w0, const float* w1, const float* w2,
                 const float* w3, const float* w4, const float* w5,
                 __hip_bfloat16* o0, __hip_bfloat16* o1, __hip_bfloat16* o2,
                 __hip_bfloat16* o3, __hip_bfloat16* o4, __hip_bfloat16* o5)
{
    int t = blockIdx.x;
    const float* s; __hip_bfloat16* dst; int Kd, Nd, tl;
    if      (t < 64)  { s = w0; dst = o0; Kd = 256;  Nd = 256;  tl = t; }
    else if (t < 128) { s = w1; dst = o1; Kd = 256;  Nd = 256;  tl = t - 64; }
    else if (t < 160) { s = w2; dst = o2; Kd = 256;  Nd = 128;  tl = t - 128; }
    else if (t < 224) { s = w3; dst = o3; Kd = 256;  Nd = 256;  tl = t - 160; }
    else if (t < 480) { s = w4; dst = o4; Kd = 256;  Nd = 1024; tl = t - 224; }
    else              { s = w5; dst = o5; Kd = 1024; Nd = 256;  tl = t - 480; }
    int ntn = Nd >> 5;
    int kt = tl / ntn, nt = tl - kt * ntn;
    __shared__ float T[32][33];
    int tx = threadIdx.x & 31, ty = threadIdx.x >> 5;
#pragma unroll
    for (int i = 0; i < 4; i++) {
        int k = kt * 32 + ty + i * 8;
        T[tx][ty + i * 8] = s[(size_t)k * Nd + nt * 32 + tx];
    }
    __syncthreads();
#pragma unroll
    for (int i = 0; i < 4; i++) {
        int n = nt * 32 + ty + i * 8;
        dst[(size_t)n * Kd + kt * 32 + tx] = __float2bfloat16(T[ty + i * 8][tx]);
    }
}

// ---------------------------------------------------------------------------
// Deformable bilinear sampling (R8 version, 44.7 us best). Block = 8 queries,
// LDS 4B/entry, stride-65, 16-deep batched 16B gathers.
// ---------------------------------------------------------------------------
#define QB 8
__global__ __launch_bounds__(256, 4)
void sample_kernel(const float* __restrict__ refp, const float* __restrict__ offb,
                   const float* __restrict__ attn,
                   const __hip_bfloat16* __restrict__ value,
                   __hip_bfloat16* __restrict__ tgt2)
{
    __shared__ unsigned spk[64 * 65];       // [sc=lp*4+c][g=ql*8+h]

    const int q0  = blockIdx.x * QB;
    const int tid = threadIdx.x;

#pragma unroll
    for (int k = 0; k < 4; k++) {
        const int it = tid + k * 256;        // (ql,h,lp)
        const int ql = it >> 7, h = (it >> 4) & 7, lp = it & 15;
        const int l = lp >> 2, p = lp & 3;
        const int q = q0 + ql, b = q >> 13;
        const int Wl = 128 >> l;
        const int LST = (l == 0) ? 0 : (l == 1) ? 16384 : (l == 2) ? 20480 : 21504;

        const float rx = refp[((size_t)q * N_LEVELS + l) * 2 + 0];
        const float ry = refp[((size_t)q * N_LEVELS + l) * 2 + 1];
        const float ox = offb[(size_t)q * 256 + h * 32 + l * 8 + p * 2 + 0];
        const float oy = offb[(size_t)q * 256 + h * 32 + l * 8 + p * 2 + 1];
        const float a  = attn[(size_t)q * 128 + h * 16 + lp];

        const float x = rx * Wl - 0.5f + ox;
        const float y = ry * Wl - 0.5f + oy;
        const float x0f = floorf(x), y0f = floorf(y);
        const float wx = x - x0f, wy = y - y0f;
        const int ix = (int)x0f, iy = (int)y0f;
        const int base = b * S_TOTAL + LST;
        const int g = ql * 8 + h;
        const float cw[4] = {(1.f - wx) * (1.f - wy) * a, wx * (1.f - wy) * a,
                             (1.f - wx) * wy * a,         wx * wy * a};
#pragma unroll
        for (int c = 0; c < 4; c++) {
            const int xi = ix + (c & 1), yi = iy + (c >> 1);
            const bool valid = ((unsigned)xi < (unsigned)Wl) && ((unsigned)yi < (unsigned)Wl);
            const unsigned pix = valid ? (unsigned)(base + yi * Wl + xi) : (unsigned)base;
            const __half hw = __float2half(valid ? cw[c] : 0.f);
            spk[(lp * 4 + c) * 65 + g] = (pix << 16) | (unsigned)__half_as_ushort(hw);
        }
    }
    __syncthreads();

    const int ql = tid >> 5, h = (tid >> 2) & 7, d4 = tid & 3;
    const int q = q0 + ql, g = ql * 8 + h;
    const int c0 = h * 32 + d4 * 8;
    const char* vb = (const char*)value + (size_t)c0 * 2;

    float ac[8] = {0.f, 0.f, 0.f, 0.f, 0.f, 0.f, 0.f, 0.f};
#pragma unroll
    for (int ch = 0; ch < 4; ch++) {
        unsigned us[16];
#pragma unroll
        for (int j = 0; j < 16; j++) us[j] = spk[(ch * 16 + j) * 65 + g];
        uint4 rv[16];
#pragma unroll
        for (int j = 0; j < 16; j++)
            rv[j] = *(const uint4*)(vb + ((size_t)(us[j] >> 16) << 9));
#pragma unroll
        for (int j = 0; j < 16; j++) {
            float wv = __half2float(__ushort_as_half((unsigned short)(us[j] & 0xffffu)));
            ac[0] += wv * __uint_as_float(rv[j].x << 16);
            ac[1] += wv * __uint_as_float(rv[j].x & 0xffff0000u);
            ac[2] += wv * __uint_as_float(rv[j].y << 16);
            ac[3] += wv * __uint_as_float(rv[j].y & 0xffff0000u);
            ac[4] += wv * __uint_as_float(rv[j].z << 16);
            ac[5] += wv * __uint_as_float(rv[j].z & 0xffff0000u);
            ac[6] += wv * __uint_as_float(rv[j].w << 16);
            ac[7] += wv * __uint_as_float(rv[j].w & 0xffff0000u);
        }
    }
    bh8 o;
#pragma unroll
    for (int i = 0; i < 8; i++) o.v[i] = __float2bfloat16(ac[i]);
    *(bh8*)(tgt2 + (size_t)q * 256 + c0) = o;
}

// ---------------------------------------------------------------------------
extern "C" void kernel_launch(void* const* d_in, const int* in_sizes, int n_in,
                              void* d_out, int out_size, void* d_ws, size_t ws_size,
                              hipStream_t stream) {
    const float* tgt     = (const float*)d_in[0];
    const float* qpos    = (const float*)d_in[1];
    const float* refp    = (const float*)d_in[2];
    const float* src     = (const float*)d_in[3];
    const float* W_value = (const float*)d_in[6];
    const float* b_value = (const float*)d_in[7];
    const float* W_off   = (const float*)d_in[8];
    const float* b_off   = (const float*)d_in[9];
    const float* W_attn  = (const float*)d_in[10];
    const float* b_attn  = (const float*)d_in[11];
    const float* W_out   = (const float*)d_in[12];
    const float* b_out   = (const float*)d_in[13];
    const float* ln1_g   = (const float*)d_in[14];
    const float* ln1_b   = (const float*)d_in[15];
    const float* W1      = (const float*)d_in[16];
    const float* b1      = (const float*)d_in[17];
    const float* W2      = (const float*)d_in[18];
    const float* b2      = (const float*)d_in[19];
    const float* ln3_g   = (const float*)d_in[20];
    const float* ln3_b   = (const float*)d_in[21];
    float* out = (float*)d_out;

    // workspace layout
    char* p = (char*)d_ws;
    auto nxt = [&](size_t b) { char* r = p; p += (b + 255) & ~(size_t)255; return r; };
    __hip_bfloat16* Wvt    = (__hip_bfloat16*)nxt((size_t)256 * 256 * 2);
    __hip_bfloat16* Woat   = (__hip_bfloat16*)nxt((size_t)384 * 256 * 2);
    __hip_bfloat16* Woutt  = (__hip_bfloat16*)nxt((size_t)256 * 256 * 2);
    __hip_bfloat16* W1t    = (__hip_bfloat16*)nxt((size_t)1024 * 256 * 2);
    __hip_bfloat16* W2t    = (__hip_bfloat16*)nxt((size_t)256 * 1024 * 2);
    __hip_bfloat16* valueb = (__hip_bfloat16*)nxt((size_t)M_V * 256 * 2);  // dead after sampler
    float*          offb   = (float*)nxt((size_t)M_Q * 256 * 4);           // dead after sampler
    float*          attnb  = (float*)nxt((size_t)M_Q * 128 * 4);
    __hip_bfloat16* tgt2b  = (__hip_bfloat16*)nxt((size_t)M_Q * 256 * 2);
    __hip_bfloat16* t2ob   = (__hip_bfloat16*)nxt((size_t)M_Q * 256 * 2);
    float*          x      = (float*)nxt((size_t)M_Q * 256 * 4);
    __hip_bfloat16* xb     = (__hip_bfloat16*)nxt((size_t)M_Q * 256 * 2);
    __hip_bfloat16* hb     = (__hip_bfloat16*)nxt((size_t)M_Q * 1024 * 2);
    // FFN2 output (f32, 16.8 MB) overlays valueb (dead after sampler)
    float* f2o = (float*)valueb;

    dim3 blk(256);

    // 0) prep: weight transpose+cvt only
    prep_kernel<<<dim3(736), blk, 0, stream>>>(
        W_value, W_off, W_attn, W_out, W1, W2,
        Wvt, Woat, Woat + 256 * 256, Woutt, W1t, W2t);

    // 1) value GEMM ++ off/attn GEMM (64x64, fused cvt BK=64, XCD swizzle)
    mfma_gemm_vq<<<dim3(VT64 * 4 + 256 / 8 * 48), blk, 0, stream>>>(
        src, Wvt, b_value, valueb, tgt, qpos, Woat, b_off, b_attn, offb, attnb);

    // 2) deformable sampling -> tgt2 (bf16)
    sample_kernel<<<dim3(M_Q / QB), blk, 0, stream>>>(refp, offb, attnb, valueb, tgt2b);

    // 3) t2o = tgt2 @ W_out + b_out -> bf16  (COLS=4, 1024 blocks)
    mfma_gemm64<256, 1, 4><<<dim3(M_Q / 64 * 4), blk, 0, stream>>>(
        tgt2b, Woutt, b_out, nullptr, t2ob, 256, 256, 256);

    // 4) x = LN1(tgt + t2o) -> f32 + bf16
    ln_kernel<true><<<dim3(M_Q / 4), blk, 0, stream>>>(
        nullptr, t2ob, nullptr, tgt, nullptr, ln1_g, ln1_b, x, xb);

    // 5) h = relu(x @ W1 + b1) -> bf16  (COLS=16, 4096 blocks)
    mfma_gemm64<256, 2, 16><<<dim3(M_Q / 64 * 16), blk, 0, stream>>>(
        xb, W1t, b1, nullptr, hb, 256, 256, 1024);

    // 6) f2o = h @ W2 + b2 -> f32, K=1024  (COLS=4, 1024 blocks)
    mfma_gemm64<1024, 0, 4><<<dim3(M_Q / 64 * 4), blk, 0, stream>>>(
        hb, W2t, b2, f2o, nullptr, 1024, 1024, 256);

    // 7) out = LN3(x + f2o) -> f32
    ln_kernel<false><<<dim3(M_Q / 4), blk, 0, stream>>>(
        f2o, nullptr, nullptr, x, nullptr, ln3_g, ln3_b, out, nullptr);
}

// Round 15
// 285.340 us; speedup vs baseline: 1.1088x; 1.0103x over previous
//
#include <hip/hip_runtime.h>
#include <hip/hip_bf16.h>
#include <hip/hip_fp16.h>
#include <math.h>

// Problem constants (fixed by setup_inputs)
#define D_MODEL   256
#define D_FFN     1024
#define N_LEVELS  4
#define N_HEADS   8
#define N_POINTS  4
#define BATCH     2
#define LQ        8192
#define S_TOTAL   21760            // 128*128 + 64*64 + 32*32 + 16*16
#define M_Q       (BATCH*LQ)       // 16384
#define M_V       (BATCH*S_TOTAL)  // 43520
#define VT64      (M_V/64)         // 680 row tiles for value GEMM

typedef __attribute__((ext_vector_type(8))) short bf16x8;   // 8 bf16 = 4 VGPRs
typedef __attribute__((ext_vector_type(4))) float floatx4;  // mfma C/D

struct alignas(8)  bh4 { __hip_bfloat16 a, b, c, d; };
struct alignas(16) bh8 { __hip_bfloat16 v[8]; };

__device__ __forceinline__ void gld_lds16(const void* g, void* l) {
    __builtin_amdgcn_global_load_lds(
        (const __attribute__((address_space(1))) void*)g,
        (__attribute__((address_space(3))) void*)l, 16, 0, 0);
}

__device__ __forceinline__ bh4 pack4(float4 a) {
    return { __float2bfloat16(a.x), __float2bfloat16(a.y),
             __float2bfloat16(a.z), __float2bfloat16(a.w) };
}

// ---------------------------------------------------------------------------
// 64x64 bf16 MFMA core. R14: BK=64 double-buffer (pattern that WON in R13's
// cvt core: vq 61.5->56 us by halving barrier count). Session ledger:
//  - R1: 128^2 tile regressed (short-K: TLP > tile area)
//  - R3: counted-vmcnt distance-2 at BK=32 NEUTRAL (same barrier count)
//  - R7/R9: wave-private L2-direct FFN regressed
//  - R13: BK=64 cvt core WIN (-8% vq, total 288.3) -> barrier COUNT is the
//    lever, not prefetch distance. Propagate to this core.
// Barriers: K=256 8->4, K=1024 32->16. LDS 24->32 KB (5 blk/CU cap > 2.8
// measured residency).
// ---------------------------------------------------------------------------
template<int K>
__device__ __forceinline__ void gemm_core64(const __hip_bfloat16* __restrict__ A,
                                            const __hip_bfloat16* __restrict__ Bt,
                                            int row0, int nb0, int lda, int ldb,
                                            short* As, short* Bs, floatx4 (&acc)[4])
{
    constexpr int NST = K / 64;                  // stages of 64 k
    static_assert(K % 64 == 0 && NST >= 2, "");
    const int tid  = threadIdx.x;
    const int w    = tid >> 6;
    const int lane = tid & 63;
    const int quad = lane >> 4;
    const int l15  = lane & 15;
    const size_t ldaB = (size_t)lda * 2, ldbB = (size_t)ldb * 2;

    const int o = w * 1024 + lane * 16;          // byte offset in 4KB 32-k tile
    const char* gA = (const char*)A + (size_t)(row0 + (o >> 6)) * ldaB + (o & 63);
    const char* gB = (const char*)Bt + (size_t)(nb0 + (o >> 6)) * ldbB + (o & 63);
    const int lofs = w * 512;                    // shorts

    auto stage = [&](int s, short* bufA, short* bufB) {  // 64-k = 2x32-k tiles
        const size_t kb = (size_t)s * 128;               // 64 k * 2 B
        gld_lds16(gA + kb,      bufA + lofs);
        gld_lds16(gA + kb + 64, bufA + 2048 + lofs);
        gld_lds16(gB + kb,      bufB + lofs);
        gld_lds16(gB + kb + 64, bufB + 2048 + lofs);
    };

    stage(0, As, Bs);

#pragma unroll
    for (int s = 0; s < NST; ++s) {
        __syncthreads();
        const int cb = s & 1;
        if (s + 1 < NST)
            stage(s + 1, As + (cb ^ 1) * 4096, Bs + (cb ^ 1) * 4096);
        const short* Ab = As + cb * 4096;
        const short* Bb = Bs + cb * 4096;
#pragma unroll
        for (int sub = 0; sub < 2; sub++) {
            bf16x8 af = *(const bf16x8*)&Ab[sub * 2048 + (w * 16 + l15) * 32 + quad * 8];
#pragma unroll
            for (int ni = 0; ni < 4; ni++) {
                bf16x8 bfr = *(const bf16x8*)&Bb[sub * 2048 + (ni * 16 + l15) * 32 + quad * 8];
                acc[ni] = __builtin_amdgcn_mfma_f32_16x16x32_bf16(af, bfr, acc[ni], 0, 0, 0);
            }
        }
    }
}

// ---------------------------------------------------------------------------
// 64x64 core with f32 A (optionally A+A2), cvt->bf16 during staging.
// R13 WINNER: BK=64 — two 32-k tiles per barrier (4 barriers for K=256).
// ---------------------------------------------------------------------------
template<int K, bool ADD>
__device__ __forceinline__ void gemm_core_cvt64(const float* __restrict__ Af,
                                                const float* __restrict__ A2f,
                                                const __hip_bfloat16* __restrict__ Bt,
                                                int row0, int nb0, int lda, int ldb,
                                                short* As, short* Bs, floatx4 (&acc)[4])
{
    constexpr int NST = K / 64;                  // stages of 64 k
    static_assert(K % 64 == 0 && NST >= 2, "");
    const int tid  = threadIdx.x;
    const int w    = tid >> 6;
    const int lane = tid & 63;
    const int quad = lane >> 4;
    const int l15  = lane & 15;

    const int o = w * 1024 + lane * 16;          // byte offset in 4KB B tile
    const char* gB = (const char*)Bt + (size_t)(nb0 + (o >> 6)) * ((size_t)ldb * 2) + (o & 63);
    const int lofs = w * 512;                    // shorts

    const int r0 = tid >> 3, k0 = (tid & 7) * 4;     // f32 index
    const float* gA0 = Af + (size_t)(row0 + r0) * lda + k0;        // rows 0..31
    const float* gA1 = gA0 + (size_t)32 * lda;                     // rows 32..63
    const float* gB0 = ADD ? (A2f + (size_t)(row0 + r0) * lda + k0) : nullptr;
    const float* gB1 = ADD ? (gB0 + (size_t)32 * lda) : nullptr;
    const int aofs0 = r0 * 32 + k0, aofs1 = aofs0 + 1024;

    float4 f[4];                                 // [t0r0, t0r1, t1r0, t1r1]
    auto loadA2 = [&](int kt) {                  // two 32-k tiles at kt, kt+32
        f[0] = *(const float4*)(gA0 + kt);
        f[1] = *(const float4*)(gA1 + kt);
        f[2] = *(const float4*)(gA0 + kt + 32);
        f[3] = *(const float4*)(gA1 + kt + 32);
        if (ADD) {
            float4 a0 = *(const float4*)(gB0 + kt);
            float4 a1 = *(const float4*)(gB1 + kt);
            float4 a2 = *(const float4*)(gB0 + kt + 32);
            float4 a3 = *(const float4*)(gB1 + kt + 32);
            f[0].x += a0.x; f[0].y += a0.y; f[0].z += a0.z; f[0].w += a0.w;
            f[1].x += a1.x; f[1].y += a1.y; f[1].z += a1.z; f[1].w += a1.w;
            f[2].x += a2.x; f[2].y += a2.y; f[2].z += a2.z; f[2].w += a2.w;
            f[3].x += a3.x; f[3].y += a3.y; f[3].z += a3.z; f[3].w += a3.w;
        }
    };
    auto writeA2 = [&](short* buf) {             // buf = 4096-short stage base
        *(bh4*)&buf[aofs0]        = pack4(f[0]);
        *(bh4*)&buf[aofs1]        = pack4(f[1]);
        *(bh4*)&buf[aofs0 + 2048] = pack4(f[2]);
        *(bh4*)&buf[aofs1 + 2048] = pack4(f[3]);
    };
    auto stageB = [&](int s, short* buf) {       // two gld_lds per stage
        gld_lds16(gB + (size_t)(2 * s)     * 64, buf + lofs);
        gld_lds16(gB + (size_t)(2 * s + 1) * 64, buf + 2048 + lofs);
    };

    loadA2(0);
    stageB(0, Bs);
    writeA2(As);

#pragma unroll
    for (int s = 0; s < NST; ++s) {
        __syncthreads();
        const int cb = s & 1;
        const bool more = (s + 1 < NST);
        if (more) {
            loadA2((s + 1) * 64);
            stageB(s + 1, Bs + (cb ^ 1) * 4096);
        }
        const short* Ab = As + cb * 4096;
        const short* Bb = Bs + cb * 4096;
#pragma unroll
        for (int sub = 0; sub < 2; sub++) {
            bf16x8 af = *(const bf16x8*)&Ab[sub * 2048 + (w * 16 + l15) * 32 + quad * 8];
#pragma unroll
            for (int ni = 0; ni < 4; ni++) {
                bf16x8 bfr = *(const bf16x8*)&Bb[sub * 2048 + (ni * 16 + l15) * 32 + quad * 8];
                acc[ni] = __builtin_amdgcn_mfma_f32_16x16x32_bf16(af, bfr, acc[ni], 0, 0, 0);
            }
        }
        if (more) writeA2(As + (cb ^ 1) * 4096);
    }
}

// ---------------------------------------------------------------------------
// Generic 64x64 GEMM, bf16 A (BK=64 core). 1-D grid of rows*COLS blocks with
// XCD-aware swizzle: id = g*(8*COLS) + col*8 + rowlane, so the COLS blocks
// sharing an A row-tile all have id = rowlane (mod 8) -> SAME XCD -> A
// fetched from HBM once into that XCD's L2.
// EPI: 0 f32 (+bias); 1 bf16 (+bias); 2 relu -> bf16.
// ---------------------------------------------------------------------------
template<int K, int EPI, int COLS>
__global__ __launch_bounds__(256)
void mfma_gemm64(const __hip_bfloat16* __restrict__ A,
                 const __hip_bfloat16* __restrict__ Bt,
                 const float* __restrict__ bias,
                 float* __restrict__ outf, __hip_bfloat16* __restrict__ outb,
                 int lda, int ldb, int ldOut)
{
    __shared__ alignas(16) short As[2 * 4096];
    __shared__ alignas(16) short Bs[2 * 4096];

    constexpr int BPG = 8 * COLS;
    const int g  = blockIdx.x / BPG;
    const int wq = blockIdx.x % BPG;
    const int row0 = (g * 8 + (wq & 7)) * 64;
    const int nb0  = (wq >> 3) * 64;

    const int tid = threadIdx.x, w = tid >> 6, lane = tid & 63;
    const int quad = lane >> 4, l15 = lane & 15;

    floatx4 acc[4];
#pragma unroll
    for (int ni = 0; ni < 4; ni++) acc[ni] = (floatx4){0.f, 0.f, 0.f, 0.f};

    gemm_core64<K>(A, Bt, row0, nb0, lda, ldb, As, Bs, acc);

    float bias_c[4];
#pragma unroll
    for (int ni = 0; ni < 4; ni++) bias_c[ni] = bias ? bias[nb0 + ni * 16 + l15] : 0.f;

#pragma unroll
    for (int r = 0; r < 4; r++) {
        int row = row0 + w * 16 + quad * 4 + r;
        size_t rb = (size_t)row * ldOut + nb0;
#pragma unroll
        for (int ni = 0; ni < 4; ni++) {
            float v = acc[ni][r] + bias_c[ni];
            if (EPI == 2)      outb[rb + ni * 16 + l15] = __float2bfloat16(fmaxf(v, 0.f));
            else if (EPI == 1) outb[rb + ni * 16 + l15] = __float2bfloat16(v);
            else               outf[rb + ni * 16 + l15] = v;
        }
    }
}

// ---------------------------------------------------------------------------
// Merged value-projection + off/attn GEMM (64x64, fused cvt BK=64, R13
// winner), 1-D grid with the same XCD-aware swizzle.
// ids [0, 2720): value part — groups of 32 = 8 rows x 4 cols.
// ids [2720, 4256): off/attn — groups of 48 = 8 rows x 6 cols
//   (col<4 -> off cols c*64, f32 ld 256; col>=4 -> attn, softmax16, ld 128).
// ---------------------------------------------------------------------------
__global__ __launch_bounds__(256)
void mfma_gemm_vq(const float* __restrict__ src,
                  const __hip_bfloat16* __restrict__ Wvt,
                  const float* __restrict__ b_value,
                  __hip_bfloat16* __restrict__ valueb,
                  const float* __restrict__ tgt, const float* __restrict__ qpos,
                  const __hip_bfloat16* __restrict__ Woat,
                  const float* __restrict__ b_off, const float* __restrict__ b_attn,
                  float* __restrict__ offb, float* __restrict__ attnb)
{
    __shared__ alignas(16) short As[2 * 4096];
    __shared__ alignas(16) short Bs[2 * 4096];

    const int id = blockIdx.x;
    const int tid = threadIdx.x, w = tid >> 6, lane = tid & 63;
    const int quad = lane >> 4, l15 = lane & 15;

    floatx4 acc[4];
#pragma unroll
    for (int ni = 0; ni < 4; ni++) acc[ni] = (floatx4){0.f, 0.f, 0.f, 0.f};

    if (id < VT64 * 4) {     // value part
        const int g = id >> 5, wq = id & 31;
        const int row0 = (g * 8 + (wq & 7)) * 64;
        const int nb0  = (wq >> 3) * 64;
        gemm_core_cvt64<256, false>(src, nullptr, Wvt, row0, nb0, 256, 256, As, Bs, acc);
        float bias_c[4];
#pragma unroll
        for (int ni = 0; ni < 4; ni++) bias_c[ni] = b_value[nb0 + ni * 16 + l15];
#pragma unroll
        for (int r = 0; r < 4; r++) {
            int row = row0 + w * 16 + quad * 4 + r;
            size_t rb = (size_t)row * 256 + nb0;
#pragma unroll
            for (int ni = 0; ni < 4; ni++)
                valueb[rb + ni * 16 + l15] = __float2bfloat16(acc[ni][r] + bias_c[ni]);
        }
        return;
    }

    const int oid = id - VT64 * 4;
    const int g = oid / 48, wq = oid % 48;
    const int row0 = (g * 8 + (wq & 7)) * 64;
    const int c = wq >> 3;   // 0..5

    if (c < 4) {             // offsets: cols c*64 of Woat, f32 out ld 256
        const int nb0 = c * 64;
        gemm_core_cvt64<256, true>(tgt, qpos, Woat, row0, nb0, 256, 256, As, Bs, acc);
        float bias_c[4];
#pragma unroll
        for (int ni = 0; ni < 4; ni++) bias_c[ni] = b_off[nb0 + ni * 16 + l15];
#pragma unroll
        for (int r = 0; r < 4; r++) {
            int row = row0 + w * 16 + quad * 4 + r;
            size_t rb = (size_t)row * 256 + nb0;
#pragma unroll
            for (int ni = 0; ni < 4; ni++)
                offb[rb + ni * 16 + l15] = acc[ni][r] + bias_c[ni];
        }
    } else {                 // attn: Woat rows 256 + (c-4)*64; softmax16
        const int c0 = (c - 4) * 64;
        gemm_core_cvt64<256, true>(tgt, qpos, Woat, row0, 256 + c0, 256, 256, As, Bs, acc);
        float bias_c[4];
#pragma unroll
        for (int ni = 0; ni < 4; ni++) bias_c[ni] = b_attn[c0 + ni * 16 + l15];
#pragma unroll
        for (int r = 0; r < 4; r++) {
            int row = row0 + w * 16 + quad * 4 + r;
            size_t rb = (size_t)row * 128 + c0;
#pragma unroll
            for (int ni = 0; ni < 4; ni++) {
                float v = acc[ni][r] + bias_c[ni];
                float m = v;
#pragma unroll
                for (int msk = 1; msk <= 8; msk <<= 1) m = fmaxf(m, __shfl_xor(m, msk));
                float e = __expf(v - m);
                float ssum = e;
#pragma unroll
                for (int msk = 1; msk <= 8; msk <<= 1) ssum += __shfl_xor(ssum, msk);
                attnb[rb + ni * 16 + l15] = e / ssum;
            }
        }
    }
}

// ---------------------------------------------------------------------------
// Residual + LayerNorm, one wave per 256-col row.
// v = resid + in1 (+ in2) (+ bias). B1: in1 is bf16.
// ---------------------------------------------------------------------------
template<bool B1>
__global__ __launch_bounds__(256)
void ln_kernel(const float* __restrict__ in1f, const __hip_bfloat16* __restrict__ in1b,
               const float* __restrict__ in2,
               const float* __restrict__ resid, const float* __restrict__ bias,
               const float* __restrict__ g, const float* __restrict__ b,
               float* __restrict__ outf, __hip_bfloat16* __restrict__ outb)
{
    const int row  = blockIdx.x * 4 + (threadIdx.x >> 6);
    const int lane = threadIdx.x & 63;
    const size_t rb = (size_t)row * 256 + lane * 4;

    float4 v = *(const float4*)(resid + rb);
    if (B1) {
        bh4 a = *(const bh4*)(in1b + rb);
        v.x += __bfloat162float(a.a); v.y += __bfloat162float(a.b);
        v.z += __bfloat162float(a.c); v.w += __bfloat162float(a.d);
    } else {
        float4 a = *(const float4*)(in1f + rb);
        v.x += a.x; v.y += a.y; v.z += a.z; v.w += a.w;
    }
    if (in2) {
        float4 c = *(const float4*)(in2 + rb);
        v.x += c.x; v.y += c.y; v.z += c.z; v.w += c.w;
    }
    if (bias) {
        float4 c = *(const float4*)(bias + lane * 4);
        v.x += c.x; v.y += c.y; v.z += c.z; v.w += c.w;
    }
    float s  = v.x + v.y + v.z + v.w;
    float sq = v.x * v.x + v.y * v.y + v.z * v.z + v.w * v.w;
#pragma unroll
    for (int msk = 1; msk <= 32; msk <<= 1) {
        s += __shfl_xor(s, msk); sq += __shfl_xor(sq, msk);
    }
    float mean = s * (1.f / 256.f);
    float var  = sq * (1.f / 256.f) - mean * mean;
    float rstd = rsqrtf(var + 1e-5f);
    float4 gg = *(const float4*)(g + lane * 4);
    float4 bb = *(const float4*)(b + lane * 4);
    float4 o;
    o.x = (v.x - mean) * rstd * gg.x + bb.x;
    o.y = (v.y - mean) * rstd * gg.y + bb.y;
    o.z = (v.z - mean) * rstd * gg.z + bb.z;
    o.w = (v.w - mean) * rstd * gg.w + bb.w;
    *(float4*)(outf + rb) = o;
    if (outb)
        *(bh4*)(outb + rb) = { __float2bfloat16(o.x), __float2bfloat16(o.y),
                               __float2bfloat16(o.z), __float2bfloat16(o.w) };
}

// ---------------------------------------------------------------------------
// Prep: weight transpose + f32->bf16 only (736 tiles of 32x32)
// ---------------------------------------------------------------------------
__global__ __launch_bounds__(256)
void prep_kernel(const float* w0, const float* w1, const float* w2,
                 const float* w3, const float* w4, const float* w5,
                 __hip_bfloat16* o0, __hip_bfloat16* o1, __hip_bfloat16* o2,
                 __hip_bfloat16* o3, __hip_bfloat16* o4, __hip_bfloat16* o5)
{
    int t = blockIdx.x;
    const float* s; __hip_bfloat16* dst; int Kd, Nd, tl;
    if      (t < 64)  { s = w0; dst = o0; Kd = 256;  Nd = 256;  tl = t; }
    else if (t < 128) { s = w1; dst = o1; Kd = 256;  Nd = 256;  tl = t - 64; }
    else if (t < 160) { s = w2; dst = o2; Kd = 256;  Nd = 128;  tl = t - 128; }
    else if (t < 224) { s = w3; dst = o3; Kd = 256;  Nd = 256;  tl = t - 160; }
    else if (t < 480) { s = w4; dst = o4; Kd = 256;  Nd = 1024; tl = t - 224; }
    else              { s = w5; dst = o5; Kd = 1024; Nd = 256;  tl = t - 480; }
    int ntn = Nd >> 5;
    int kt = tl / ntn, nt = tl - kt * ntn;
    __shared__ float T[32][33];
    int tx = threadIdx.x & 31, ty = threadIdx.x >> 5;
#pragma unroll
    for (int i = 0; i < 4; i++) {
        int k = kt * 32 + ty + i * 8;
        T[tx][ty + i * 8] = s[(size_t)k * Nd + nt * 32 + tx];
    }
    __syncthreads();
#pragma unroll
    for (int i = 0; i < 4; i++) {
        int n = nt * 32 + ty + i * 8;
        dst[(size_t)n * Kd + kt * 32 + tx] = __float2bfloat16(T[ty + i * 8][tx]);
    }
}

// ---------------------------------------------------------------------------
// Deformable bilinear sampling (R8 version, 44.7 us best). Block = 8 queries,
// LDS 4B/entry, stride-65, 16-deep batched 16B gathers.
// ---------------------------------------------------------------------------
#define QB 8
__global__ __launch_bounds__(256, 4)
void sample_kernel(const float* __restrict__ refp, const float* __restrict__ offb,
                   const float* __restrict__ attn,
                   const __hip_bfloat16* __restrict__ value,
                   __hip_bfloat16* __restrict__ tgt2)
{
    __shared__ unsigned spk[64 * 65];       // [sc=lp*4+c][g=ql*8+h]

    const int q0  = blockIdx.x * QB;
    const int tid = threadIdx.x;

#pragma unroll
    for (int k = 0; k < 4; k++) {
        const int it = tid + k * 256;        // (ql,h,lp)
        const int ql = it >> 7, h = (it >> 4) & 7, lp = it & 15;
        const int l = lp >> 2, p = lp & 3;
        const int q = q0 + ql, b = q >> 13;
        const int Wl = 128 >> l;
        const int LST = (l == 0) ? 0 : (l == 1) ? 16384 : (l == 2) ? 20480 : 21504;

        const float rx = refp[((size_t)q * N_LEVELS + l) * 2 + 0];
        const float ry = refp[((size_t)q * N_LEVELS + l) * 2 + 1];
        const float ox = offb[(size_t)q * 256 + h * 32 + l * 8 + p * 2 + 0];
        const float oy = offb[(size_t)q * 256 + h * 32 + l * 8 + p * 2 + 1];
        const float a  = attn[(size_t)q * 128 + h * 16 + lp];

        const float x = rx * Wl - 0.5f + ox;
        const float y = ry * Wl - 0.5f + oy;
        const float x0f = floorf(x), y0f = floorf(y);
        const float wx = x - x0f, wy = y - y0f;
        const int ix = (int)x0f, iy = (int)y0f;
        const int base = b * S_TOTAL + LST;
        const int g = ql * 8 + h;
        const float cw[4] = {(1.f - wx) * (1.f - wy) * a, wx * (1.f - wy) * a,
                             (1.f - wx) * wy * a,         wx * wy * a};
#pragma unroll
        for (int c = 0; c < 4; c++) {
            const int xi = ix + (c & 1), yi = iy + (c >> 1);
            const bool valid = ((unsigned)xi < (unsigned)Wl) && ((unsigned)yi < (unsigned)Wl);
            const unsigned pix = valid ? (unsigned)(base + yi * Wl + xi) : (unsigned)base;
            const __half hw = __float2half(valid ? cw[c] : 0.f);
            spk[(lp * 4 + c) * 65 + g] = (pix << 16) | (unsigned)__half_as_ushort(hw);
        }
    }
    __syncthreads();

    const int ql = tid >> 5, h = (tid >> 2) & 7, d4 = tid & 3;
    const int q = q0 + ql, g = ql * 8 + h;
    const int c0 = h * 32 + d4 * 8;
    const char* vb = (const char*)value + (size_t)c0 * 2;

    float ac[8] = {0.f, 0.f, 0.f, 0.f, 0.f, 0.f, 0.f, 0.f};
#pragma unroll
    for (int ch = 0; ch < 4; ch++) {
        unsigned us[16];
#pragma unroll
        for (int j = 0; j < 16; j++) us[j] = spk[(ch * 16 + j) * 65 + g];
        uint4 rv[16];
#pragma unroll
        for (int j = 0; j < 16; j++)
            rv[j] = *(const uint4*)(vb + ((size_t)(us[j] >> 16) << 9));
#pragma unroll
        for (int j = 0; j < 16; j++) {
            float wv = __half2float(__ushort_as_half((unsigned short)(us[j] & 0xffffu)));
            ac[0] += wv * __uint_as_float(rv[j].x << 16);
            ac[1] += wv * __uint_as_float(rv[j].x & 0xffff0000u);
            ac[2] += wv * __uint_as_float(rv[j].y << 16);
            ac[3] += wv * __uint_as_float(rv[j].y & 0xffff0000u);
            ac[4] += wv * __uint_as_float(rv[j].z << 16);
            ac[5] += wv * __uint_as_float(rv[j].z & 0xffff0000u);
            ac[6] += wv * __uint_as_float(rv[j].w << 16);
            ac[7] += wv * __uint_as_float(rv[j].w & 0xffff0000u);
        }
    }
    bh8 o;
#pragma unroll
    for (int i = 0; i < 8; i++) o.v[i] = __float2bfloat16(ac[i]);
    *(bh8*)(tgt2 + (size_t)q * 256 + c0) = o;
}

// ---------------------------------------------------------------------------
extern "C" void kernel_launch(void* const* d_in, const int* in_sizes, int n_in,
                              void* d_out, int out_size, void* d_ws, size_t ws_size,
                              hipStream_t stream) {
    const float* tgt     = (const float*)d_in[0];
    const float* qpos    = (const float*)d_in[1];
    const float* refp    = (const float*)d_in[2];
    const float* src     = (const float*)d_in[3];
    const float* W_value = (const float*)d_in[6];
    const float* b_value = (const float*)d_in[7];
    const float* W_off   = (const float*)d_in[8];
    const float* b_off   = (const float*)d_in[9];
    const float* W_attn  = (const float*)d_in[10];
    const float* b_attn  = (const float*)d_in[11];
    const float* W_out   = (const float*)d_in[12];
    const float* b_out   = (const float*)d_in[13];
    const float* ln1_g   = (const float*)d_in[14];
    const float* ln1_b   = (const float*)d_in[15];
    const float* W1      = (const float*)d_in[16];
    const float* b1      = (const float*)d_in[17];
    const float* W2      = (const float*)d_in[18];
    const float* b2      = (const float*)d_in[19];
    const float* ln3_g   = (const float*)d_in[20];
    const float* ln3_b   = (const float*)d_in[21];
    float* out = (float*)d_out;

    // workspace layout
    char* p = (char*)d_ws;
    auto nxt = [&](size_t b) { char* r = p; p += (b + 255) & ~(size_t)255; return r; };
    __hip_bfloat16* Wvt    = (__hip_bfloat16*)nxt((size_t)256 * 256 * 2);
    __hip_bfloat16* Woat   = (__hip_bfloat16*)nxt((size_t)384 * 256 * 2);
    __hip_bfloat16* Woutt  = (__hip_bfloat16*)nxt((size_t)256 * 256 * 2);
    __hip_bfloat16* W1t    = (__hip_bfloat16*)nxt((size_t)1024 * 256 * 2);
    __hip_bfloat16* W2t    = (__hip_bfloat16*)nxt((size_t)256 * 1024 * 2);
    __hip_bfloat16* valueb = (__hip_bfloat16*)nxt((size_t)M_V * 256 * 2);  // dead after sampler
    float*          offb   = (float*)nxt((size_t)M_Q * 256 * 4);           // dead after sampler
    float*          attnb  = (float*)nxt((size_t)M_Q * 128 * 4);
    __hip_bfloat16* tgt2b  = (__hip_bfloat16*)nxt((size_t)M_Q * 256 * 2);
    __hip_bfloat16* t2ob   = (__hip_bfloat16*)nxt((size_t)M_Q * 256 * 2);
    float*          x      = (float*)nxt((size_t)M_Q * 256 * 4);
    __hip_bfloat16* xb     = (__hip_bfloat16*)nxt((size_t)M_Q * 256 * 2);
    __hip_bfloat16* hb     = (__hip_bfloat16*)nxt((size_t)M_Q * 1024 * 2);
    // FFN2 output (f32, 16.8 MB) overlays valueb (dead after sampler)
    float* f2o = (float*)valueb;

    dim3 blk(256);

    // 0) prep: weight transpose+cvt only
    prep_kernel<<<dim3(736), blk, 0, stream>>>(
        W_value, W_off, W_attn, W_out, W1, W2,
        Wvt, Woat, Woat + 256 * 256, Woutt, W1t, W2t);

    // 1) value GEMM ++ off/attn GEMM (64x64, fused cvt BK=64, XCD swizzle)
    mfma_gemm_vq<<<dim3(VT64 * 4 + 256 / 8 * 48), blk, 0, stream>>>(
        src, Wvt, b_value, valueb, tgt, qpos, Woat, b_off, b_attn, offb, attnb);

    // 2) deformable sampling -> tgt2 (bf16)
    sample_kernel<<<dim3(M_Q / QB), blk, 0, stream>>>(refp, offb, attnb, valueb, tgt2b);

    // 3) t2o = tgt2 @ W_out + b_out -> bf16  (COLS=4, 1024 blocks)
    mfma_gemm64<256, 1, 4><<<dim3(M_Q / 64 * 4), blk, 0, stream>>>(
        tgt2b, Woutt, b_out, nullptr, t2ob, 256, 256, 256);

    // 4) x = LN1(tgt + t2o) -> f32 + bf16
    ln_kernel<true><<<dim3(M_Q / 4), blk, 0, stream>>>(
        nullptr, t2ob, nullptr, tgt, nullptr, ln1_g, ln1_b, x, xb);

    // 5) h = relu(x @ W1 + b1) -> bf16  (COLS=16, 4096 blocks)
    mfma_gemm64<256, 2, 16><<<dim3(M_Q / 64 * 16), blk, 0, stream>>>(
        xb, W1t, b1, nullptr, hb, 256, 256, 1024);

    // 6) f2o = h @ W2 + b2 -> f32, K=1024  (COLS=4, 1024 blocks)
    mfma_gemm64<1024, 0, 4><<<dim3(M_Q / 64 * 4), blk, 0, stream>>>(
        hb, W2t, b2, f2o, nullptr, 1024, 1024, 256);

    // 7) out = LN3(x + f2o) -> f32
    ln_kernel<false><<<dim3(M_Q / 4), blk, 0, stream>>>(
        f2o, nullptr, nullptr, x, nullptr, ln3_g, ln3_b, out, nullptr);
}

// Round 16
// 284.250 us; speedup vs baseline: 1.1130x; 1.0038x over previous
//
#include <hip/hip_runtime.h>
#include <hip/hip_bf16.h>
#include <hip/hip_fp16.h>
#include <math.h>

// Problem constants (fixed by setup_inputs)
#define D_MODEL   256
#define D_FFN     1024
#define N_LEVELS  4
#define N_HEADS   8
#define N_POINTS  4
#define BATCH     2
#define LQ        8192
#define S_TOTAL   21760            // 128*128 + 64*64 + 32*32 + 16*16
#define M_Q       (BATCH*LQ)       // 16384
#define M_V       (BATCH*S_TOTAL)  // 43520
#define VT64      (M_V/64)         // 680 row tiles for value GEMM

typedef __attribute__((ext_vector_type(8))) short bf16x8;   // 8 bf16 = 4 VGPRs
typedef __attribute__((ext_vector_type(4))) float floatx4;  // mfma C/D

struct alignas(8)  bh4 { __hip_bfloat16 a, b, c, d; };
struct alignas(16) bh8 { __hip_bfloat16 v[8]; };

__device__ __forceinline__ void gld_lds16(const void* g, void* l) {
    __builtin_amdgcn_global_load_lds(
        (const __attribute__((address_space(1))) void*)g,
        (__attribute__((address_space(3))) void*)l, 16, 0, 0);
}

__device__ __forceinline__ bh4 pack4(float4 a) {
    return { __float2bfloat16(a.x), __float2bfloat16(a.y),
             __float2bfloat16(a.z), __float2bfloat16(a.w) };
}

// ---------------------------------------------------------------------------
// 64x128 bf16 MFMA core, BK=64 double-buffer. Session ledger:
//  - R13: BK=64 cvt core WIN (vq 61.5->56.5)  - barrier count is the lever
//  - R15: BK=64 bf16 core WIN (288.3->285.3)  - confirmed again
//  - R16: widen N 64->128 (8 n-frags): 2x MFMA per barrier interval, A-load
//    amortized 2x. LDS 48 KB -> 3 blk/CU cap (> measured ~2.7 residency);
//    acc 32 VGPR (est total ~85 < 128 = 4-wave cap). Blocks halve but all
//    grids stay >= 2/CU.
// LDS B layout per 64-k stage: two 32-k subtiles, each [128 N-rows][32 k]
// (4096 shorts); rows 64..127 at +2048 via second gld_lds chunk.
// ---------------------------------------------------------------------------
template<int K>
__device__ __forceinline__ void gemm_core64x128(const __hip_bfloat16* __restrict__ A,
                                                const __hip_bfloat16* __restrict__ Bt,
                                                int row0, int nb0, int lda, int ldb,
                                                short* As, short* Bs, floatx4 (&acc)[8])
{
    constexpr int NST = K / 64;                  // stages of 64 k
    static_assert(K % 64 == 0 && NST >= 2, "");
    const int tid  = threadIdx.x;
    const int w    = tid >> 6;
    const int lane = tid & 63;
    const int quad = lane >> 4;
    const int l15  = lane & 15;
    const size_t ldaB = (size_t)lda * 2, ldbB = (size_t)ldb * 2;

    const int o = w * 1024 + lane * 16;          // byte offset in 4KB 64x32 tile
    const char* gA = (const char*)A + (size_t)(row0 + (o >> 6)) * ldaB + (o & 63);
    const char* gB = (const char*)Bt + (size_t)(nb0 + (o >> 6)) * ldbB + (o & 63);
    const char* gB2 = gB + (size_t)64 * ldbB;    // N-rows 64..127
    const int lofs = w * 512;                    // shorts

    auto stage = [&](int s, short* bufA, short* bufB) {
        const size_t kb = (size_t)s * 128;       // 64 k * 2 B
        gld_lds16(gA + kb,       bufA + lofs);
        gld_lds16(gA + kb + 64,  bufA + 2048 + lofs);
#pragma unroll
        for (int sub = 0; sub < 2; sub++) {
            gld_lds16(gB  + kb + sub * 64, bufB + sub * 4096 + lofs);
            gld_lds16(gB2 + kb + sub * 64, bufB + sub * 4096 + 2048 + lofs);
        }
    };

    stage(0, As, Bs);

#pragma unroll
    for (int s = 0; s < NST; ++s) {
        __syncthreads();
        const int cb = s & 1;
        if (s + 1 < NST)
            stage(s + 1, As + (cb ^ 1) * 4096, Bs + (cb ^ 1) * 8192);
        const short* Ab = As + cb * 4096;
        const short* Bb = Bs + cb * 8192;
#pragma unroll
        for (int sub = 0; sub < 2; sub++) {
            bf16x8 af = *(const bf16x8*)&Ab[sub * 2048 + (w * 16 + l15) * 32 + quad * 8];
#pragma unroll
            for (int ni = 0; ni < 8; ni++) {
                bf16x8 bfr = *(const bf16x8*)&Bb[sub * 4096 + (ni * 16 + l15) * 32 + quad * 8];
                acc[ni] = __builtin_amdgcn_mfma_f32_16x16x32_bf16(af, bfr, acc[ni], 0, 0, 0);
            }
        }
    }
}

// ---------------------------------------------------------------------------
// 64x128 core with f32 A (optionally A+A2), cvt->bf16 during staging.
// A path identical to the R13 winner; B widened to 128 N-rows.
// ---------------------------------------------------------------------------
template<int K, bool ADD>
__device__ __forceinline__ void gemm_core_cvt64x128(const float* __restrict__ Af,
                                                    const float* __restrict__ A2f,
                                                    const __hip_bfloat16* __restrict__ Bt,
                                                    int row0, int nb0, int lda, int ldb,
                                                    short* As, short* Bs, floatx4 (&acc)[8])
{
    constexpr int NST = K / 64;                  // stages of 64 k
    static_assert(K % 64 == 0 && NST >= 2, "");
    const int tid  = threadIdx.x;
    const int w    = tid >> 6;
    const int lane = tid & 63;
    const int quad = lane >> 4;
    const int l15  = lane & 15;

    const int o = w * 1024 + lane * 16;
    const char* gB = (const char*)Bt + (size_t)(nb0 + (o >> 6)) * ((size_t)ldb * 2) + (o & 63);
    const char* gB2 = gB + (size_t)64 * ((size_t)ldb * 2);
    const int lofs = w * 512;

    const int r0 = tid >> 3, k0 = (tid & 7) * 4;     // f32 index
    const float* gA0 = Af + (size_t)(row0 + r0) * lda + k0;        // rows 0..31
    const float* gA1 = gA0 + (size_t)32 * lda;                     // rows 32..63
    const float* gC0 = ADD ? (A2f + (size_t)(row0 + r0) * lda + k0) : nullptr;
    const float* gC1 = ADD ? (gC0 + (size_t)32 * lda) : nullptr;
    const int aofs0 = r0 * 32 + k0, aofs1 = aofs0 + 1024;

    float4 f[4];                                 // [t0r0, t0r1, t1r0, t1r1]
    auto loadA2 = [&](int kt) {                  // two 32-k tiles at kt, kt+32
        f[0] = *(const float4*)(gA0 + kt);
        f[1] = *(const float4*)(gA1 + kt);
        f[2] = *(const float4*)(gA0 + kt + 32);
        f[3] = *(const float4*)(gA1 + kt + 32);
        if (ADD) {
            float4 a0 = *(const float4*)(gC0 + kt);
            float4 a1 = *(const float4*)(gC1 + kt);
            float4 a2 = *(const float4*)(gC0 + kt + 32);
            float4 a3 = *(const float4*)(gC1 + kt + 32);
            f[0].x += a0.x; f[0].y += a0.y; f[0].z += a0.z; f[0].w += a0.w;
            f[1].x += a1.x; f[1].y += a1.y; f[1].z += a1.z; f[1].w += a1.w;
            f[2].x += a2.x; f[2].y += a2.y; f[2].z += a2.z; f[2].w += a2.w;
            f[3].x += a3.x; f[3].y += a3.y; f[3].z += a3.z; f[3].w += a3.w;
        }
    };
    auto writeA2 = [&](short* buf) {             // buf = 4096-short stage base
        *(bh4*)&buf[aofs0]        = pack4(f[0]);
        *(bh4*)&buf[aofs1]        = pack4(f[1]);
        *(bh4*)&buf[aofs0 + 2048] = pack4(f[2]);
        *(bh4*)&buf[aofs1 + 2048] = pack4(f[3]);
    };
    auto stageB = [&](int s, short* buf) {       // 4 gld_lds per stage
        const size_t kb = (size_t)s * 128;
#pragma unroll
        for (int sub = 0; sub < 2; sub++) {
            gld_lds16(gB  + kb + sub * 64, buf + sub * 4096 + lofs);
            gld_lds16(gB2 + kb + sub * 64, buf + sub * 4096 + 2048 + lofs);
        }
    };

    loadA2(0);
    stageB(0, Bs);
    writeA2(As);

#pragma unroll
    for (int s = 0; s < NST; ++s) {
        __syncthreads();
        const int cb = s & 1;
        const bool more = (s + 1 < NST);
        if (more) {
            loadA2((s + 1) * 64);
            stageB(s + 1, Bs + (cb ^ 1) * 8192);
        }
        const short* Ab = As + cb * 4096;
        const short* Bb = Bs + cb * 8192;
#pragma unroll
        for (int sub = 0; sub < 2; sub++) {
            bf16x8 af = *(const bf16x8*)&Ab[sub * 2048 + (w * 16 + l15) * 32 + quad * 8];
#pragma unroll
            for (int ni = 0; ni < 8; ni++) {
                bf16x8 bfr = *(const bf16x8*)&Bb[sub * 4096 + (ni * 16 + l15) * 32 + quad * 8];
                acc[ni] = __builtin_amdgcn_mfma_f32_16x16x32_bf16(af, bfr, acc[ni], 0, 0, 0);
            }
        }
        if (more) writeA2(As + (cb ^ 1) * 4096);
    }
}

// ---------------------------------------------------------------------------
// Generic 64x128 GEMM, bf16 A. 1-D grid, XCD-aware swizzle: id = g*(8*COLS)
// + col*8 + rowlane (COLS counts 128-wide col tiles).
// EPI: 0 f32 (+bias); 1 bf16 (+bias); 2 relu -> bf16.
// ---------------------------------------------------------------------------
template<int K, int EPI, int COLS>
__global__ __launch_bounds__(256)
void mfma_gemm64(const __hip_bfloat16* __restrict__ A,
                 const __hip_bfloat16* __restrict__ Bt,
                 const float* __restrict__ bias,
                 float* __restrict__ outf, __hip_bfloat16* __restrict__ outb,
                 int lda, int ldb, int ldOut)
{
    __shared__ alignas(16) short As[2 * 4096];   // 16 KB
    __shared__ alignas(16) short Bs[2 * 8192];   // 32 KB

    constexpr int BPG = 8 * COLS;
    const int g  = blockIdx.x / BPG;
    const int wq = blockIdx.x % BPG;
    const int row0 = (g * 8 + (wq & 7)) * 64;
    const int nb0  = (wq >> 3) * 128;

    const int tid = threadIdx.x, w = tid >> 6, lane = tid & 63;
    const int quad = lane >> 4, l15 = lane & 15;

    floatx4 acc[8];
#pragma unroll
    for (int ni = 0; ni < 8; ni++) acc[ni] = (floatx4){0.f, 0.f, 0.f, 0.f};

    gemm_core64x128<K>(A, Bt, row0, nb0, lda, ldb, As, Bs, acc);

    float bias_c[8];
#pragma unroll
    for (int ni = 0; ni < 8; ni++) bias_c[ni] = bias ? bias[nb0 + ni * 16 + l15] : 0.f;

#pragma unroll
    for (int r = 0; r < 4; r++) {
        int row = row0 + w * 16 + quad * 4 + r;
        size_t rb = (size_t)row * ldOut + nb0;
#pragma unroll
        for (int ni = 0; ni < 8; ni++) {
            float v = acc[ni][r] + bias_c[ni];
            if (EPI == 2)      outb[rb + ni * 16 + l15] = __float2bfloat16(fmaxf(v, 0.f));
            else if (EPI == 1) outb[rb + ni * 16 + l15] = __float2bfloat16(v);
            else               outf[rb + ni * 16 + l15] = v;
        }
    }
}

// ---------------------------------------------------------------------------
// Merged value-projection + off/attn GEMM (64x128 tiles, fused cvt BK=64).
// ids [0, 1360): value — 85 groups of 16 = 8 rows x 2 cols (680 row tiles).
// ids [1360, 2128): off/attn — 32 groups of 24 = 8 rows x 3 cols
//   (c<2 -> off cols c*128, f32 ld 256; c==2 -> attn full 128 cols,
//    softmax16 per frag, ld 128). 1360 % 8 == 0 keeps the XCD invariant.
// ---------------------------------------------------------------------------
__global__ __launch_bounds__(256)
void mfma_gemm_vq(const float* __restrict__ src,
                  const __hip_bfloat16* __restrict__ Wvt,
                  const float* __restrict__ b_value,
                  __hip_bfloat16* __restrict__ valueb,
                  const float* __restrict__ tgt, const float* __restrict__ qpos,
                  const __hip_bfloat16* __restrict__ Woat,
                  const float* __restrict__ b_off, const float* __restrict__ b_attn,
                  float* __restrict__ offb, float* __restrict__ attnb)
{
    __shared__ alignas(16) short As[2 * 4096];   // 16 KB
    __shared__ alignas(16) short Bs[2 * 8192];   // 32 KB

    const int id = blockIdx.x;
    const int tid = threadIdx.x, w = tid >> 6, lane = tid & 63;
    const int quad = lane >> 4, l15 = lane & 15;

    floatx4 acc[8];
#pragma unroll
    for (int ni = 0; ni < 8; ni++) acc[ni] = (floatx4){0.f, 0.f, 0.f, 0.f};

    if (id < VT64 * 2) {     // value part: 64x128 tiles
        const int g = id >> 4, wq = id & 15;
        const int row0 = (g * 8 + (wq & 7)) * 64;
        const int nb0  = (wq >> 3) * 128;
        gemm_core_cvt64x128<256, false>(src, nullptr, Wvt, row0, nb0, 256, 256, As, Bs, acc);
        float bias_c[8];
#pragma unroll
        for (int ni = 0; ni < 8; ni++) bias_c[ni] = b_value[nb0 + ni * 16 + l15];
#pragma unroll
        for (int r = 0; r < 4; r++) {
            int row = row0 + w * 16 + quad * 4 + r;
            size_t rb = (size_t)row * 256 + nb0;
#pragma unroll
            for (int ni = 0; ni < 8; ni++)
                valueb[rb + ni * 16 + l15] = __float2bfloat16(acc[ni][r] + bias_c[ni]);
        }
        return;
    }

    const int oid = id - VT64 * 2;
    const int g = oid / 24, wq = oid % 24;
    const int row0 = (g * 8 + (wq & 7)) * 64;
    const int c = wq >> 3;   // 0..2

    if (c < 2) {             // offsets: cols c*128 of Woat, f32 out ld 256
        const int nb0 = c * 128;
        gemm_core_cvt64x128<256, true>(tgt, qpos, Woat, row0, nb0, 256, 256, As, Bs, acc);
        float bias_c[8];
#pragma unroll
        for (int ni = 0; ni < 8; ni++) bias_c[ni] = b_off[nb0 + ni * 16 + l15];
#pragma unroll
        for (int r = 0; r < 4; r++) {
            int row = row0 + w * 16 + quad * 4 + r;
            size_t rb = (size_t)row * 256 + nb0;
#pragma unroll
            for (int ni = 0; ni < 8; ni++)
                offb[rb + ni * 16 + l15] = acc[ni][r] + bias_c[ni];
        }
    } else {                 // attn: Woat rows 256..383 (all 128 cols); softmax16
        gemm_core_cvt64x128<256, true>(tgt, qpos, Woat, row0, 256, 256, 256, As, Bs, acc);
        float bias_c[8];
#pragma unroll
        for (int ni = 0; ni < 8; ni++) bias_c[ni] = b_attn[ni * 16 + l15];
#pragma unroll
        for (int r = 0; r < 4; r++) {
            int row = row0 + w * 16 + quad * 4 + r;
            size_t rb = (size_t)row * 128;
#pragma unroll
            for (int ni = 0; ni < 8; ni++) {
                float v = acc[ni][r] + bias_c[ni];
                float m = v;
#pragma unroll
                for (int msk = 1; msk <= 8; msk <<= 1) m = fmaxf(m, __shfl_xor(m, msk));
                float e = __expf(v - m);
                float ssum = e;
#pragma unroll
                for (int msk = 1; msk <= 8; msk <<= 1) ssum += __shfl_xor(ssum, msk);
                attnb[rb + ni * 16 + l15] = e / ssum;
            }
        }
    }
}

// ---------------------------------------------------------------------------
// Residual + LayerNorm, one wave per 256-col row.
// v = resid + in1 (+ in2) (+ bias). B1: in1 is bf16.
// ---------------------------------------------------------------------------
template<bool B1>
__global__ __launch_bounds__(256)
void ln_kernel(const float* __restrict__ in1f, const __hip_bfloat16* __restrict__ in1b,
               const float* __restrict__ in2,
               const float* __restrict__ resid, const float* __restrict__ bias,
               const float* __restrict__ g, const float* __restrict__ b,
               float* __restrict__ outf, __hip_bfloat16* __restrict__ outb)
{
    const int row  = blockIdx.x * 4 + (threadIdx.x >> 6);
    const int lane = threadIdx.x & 63;
    const size_t rb = (size_t)row * 256 + lane * 4;

    float4 v = *(const float4*)(resid + rb);
    if (B1) {
        bh4 a = *(const bh4*)(in1b + rb);
        v.x += __bfloat162float(a.a); v.y += __bfloat162float(a.b);
        v.z += __bfloat162float(a.c); v.w += __bfloat162float(a.d);
    } else {
        float4 a = *(const float4*)(in1f + rb);
        v.x += a.x; v.y += a.y; v.z += a.z; v.w += a.w;
    }
    if (in2) {
        float4 c = *(const float4*)(in2 + rb);
        v.x += c.x; v.y += c.y; v.z += c.z; v.w += c.w;
    }
    if (bias) {
        float4 c = *(const float4*)(bias + lane * 4);
        v.x += c.x; v.y += c.y; v.z += c.z; v.w += c.w;
    }
    float s  = v.x + v.y + v.z + v.w;
    float sq = v.x * v.x + v.y * v.y + v.z * v.z + v.w * v.w;
#pragma unroll
    for (int msk = 1; msk <= 32; msk <<= 1) {
        s += __shfl_xor(s, msk); sq += __shfl_xor(sq, msk);
    }
    float mean = s * (1.f / 256.f);
    float var  = sq * (1.f / 256.f) - mean * mean;
    float rstd = rsqrtf(var + 1e-5f);
    float4 gg = *(const float4*)(g + lane * 4);
    float4 bb = *(const float4*)(b + lane * 4);
    float4 o;
    o.x = (v.x - mean) * rstd * gg.x + bb.x;
    o.y = (v.y - mean) * rstd * gg.y + bb.y;
    o.z = (v.z - mean) * rstd * gg.z + bb.z;
    o.w = (v.w - mean) * rstd * gg.w + bb.w;
    *(float4*)(outf + rb) = o;
    if (outb)
        *(bh4*)(outb + rb) = { __float2bfloat16(o.x), __float2bfloat16(o.y),
                               __float2bfloat16(o.z), __float2bfloat16(o.w) };
}

// ---------------------------------------------------------------------------
// Prep: weight transpose + f32->bf16 only (736 tiles of 32x32)
// ---------------------------------------------------------------------------
__global__ __launch_bounds__(256)
void prep_kernel(const float* w0, const float* w1, const float* w2,
                 const float* w3, const float* w4, const float* w5,
                 __hip_bfloat16* o0, __hip_bfloat16* o1, __hip_bfloat16* o2,
                 __hip_bfloat16* o3, __hip_bfloat16* o4, __hip_bfloat16* o5)
{
    int t = blockIdx.x;
    const float* s; __hip_bfloat16* dst; int Kd, Nd, tl;
    if      (t < 64)  { s = w0; dst = o0; Kd = 256;  Nd = 256;  tl = t; }
    else if (t < 128) { s = w1; dst = o1; Kd = 256;  Nd = 256;  tl = t - 64; }
    else if (t < 160) { s = w2; dst = o2; Kd = 256;  Nd = 128;  tl = t - 128; }
    else if (t < 224) { s = w3; dst = o3; Kd = 256;  Nd = 256;  tl = t - 160; }
    else if (t < 480) { s = w4; dst = o4; Kd = 256;  Nd = 1024; tl = t - 224; }
    else              { s = w5; dst = o5; Kd = 1024; Nd = 256;  tl = t - 480; }
    int ntn = Nd >> 5;
    int kt = tl / ntn, nt = tl - kt * ntn;
    __shared__ float T[32][33];
    int tx = threadIdx.x & 31, ty = threadIdx.x >> 5;
#pragma unroll
    for (int i = 0; i < 4; i++) {
        int k = kt * 32 + ty + i * 8;
        T[tx][ty + i * 8] = s[(size_t)k * Nd + nt * 32 + tx];
    }
    __syncthreads();
#pragma unroll
    for (int i = 0; i < 4; i++) {
        int n = nt * 32 + ty + i * 8;
        dst[(size_t)n * Kd + kt * 32 + tx] = __float2bfloat16(T[ty + i * 8][tx]);
    }
}

// ---------------------------------------------------------------------------
// Deformable bilinear sampling (R8 version, 44.7 us best). Block = 8 queries,
// LDS 4B/entry, stride-65, 16-deep batched 16B gathers.
// ---------------------------------------------------------------------------
#define QB 8
__global__ __launch_bounds__(256, 4)
void sample_kernel(const float* __restrict__ refp, const float* __restrict__ offb,
                   const float* __restrict__ attn,
                   const __hip_bfloat16* __restrict__ value,
                   __hip_bfloat16* __restrict__ tgt2)
{
    __shared__ unsigned spk[64 * 65];       // [sc=lp*4+c][g=ql*8+h]

    const int q0  = blockIdx.x * QB;
    const int tid = threadIdx.x;

#pragma unroll
    for (int k = 0; k < 4; k++) {
        const int it = tid + k * 256;        // (ql,h,lp)
        const int ql = it >> 7, h = (it >> 4) & 7, lp = it & 15;
        const int l = lp >> 2, p = lp & 3;
        const int q = q0 + ql, b = q >> 13;
        const int Wl = 128 >> l;
        const int LST = (l == 0) ? 0 : (l == 1) ? 16384 : (l == 2) ? 20480 : 21504;

        const float rx = refp[((size_t)q * N_LEVELS + l) * 2 + 0];
        const float ry = refp[((size_t)q * N_LEVELS + l) * 2 + 1];
        const float ox = offb[(size_t)q * 256 + h * 32 + l * 8 + p * 2 + 0];
        const float oy = offb[(size_t)q * 256 + h * 32 + l * 8 + p * 2 + 1];
        const float a  = attn[(size_t)q * 128 + h * 16 + lp];

        const float x = rx * Wl - 0.5f + ox;
        const float y = ry * Wl - 0.5f + oy;
        const float x0f = floorf(x), y0f = floorf(y);
        const float wx = x - x0f, wy = y - y0f;
        const int ix = (int)x0f, iy = (int)y0f;
        const int base = b * S_TOTAL + LST;
        const int g = ql * 8 + h;
        const float cw[4] = {(1.f - wx) * (1.f - wy) * a, wx * (1.f - wy) * a,
                             (1.f - wx) * wy * a,         wx * wy * a};
#pragma unroll
        for (int c = 0; c < 4; c++) {
            const int xi = ix + (c & 1), yi = iy + (c >> 1);
            const bool valid = ((unsigned)xi < (unsigned)Wl) && ((unsigned)yi < (unsigned)Wl);
            const unsigned pix = valid ? (unsigned)(base + yi * Wl + xi) : (unsigned)base;
            const __half hw = __float2half(valid ? cw[c] : 0.f);
            spk[(lp * 4 + c) * 65 + g] = (pix << 16) | (unsigned)__half_as_ushort(hw);
        }
    }
    __syncthreads();

    const int ql = tid >> 5, h = (tid >> 2) & 7, d4 = tid & 3;
    const int q = q0 + ql, g = ql * 8 + h;
    const int c0 = h * 32 + d4 * 8;
    const char* vb = (const char*)value + (size_t)c0 * 2;

    float ac[8] = {0.f, 0.f, 0.f, 0.f, 0.f, 0.f, 0.f, 0.f};
#pragma unroll
    for (int ch = 0; ch < 4; ch++) {
        unsigned us[16];
#pragma unroll
        for (int j = 0; j < 16; j++) us[j] = spk[(ch * 16 + j) * 65 + g];
        uint4 rv[16];
#pragma unroll
        for (int j = 0; j < 16; j++)
            rv[j] = *(const uint4*)(vb + ((size_t)(us[j] >> 16) << 9));
#pragma unroll
        for (int j = 0; j < 16; j++) {
            float wv = __half2float(__ushort_as_half((unsigned short)(us[j] & 0xffffu)));
            ac[0] += wv * __uint_as_float(rv[j].x << 16);
            ac[1] += wv * __uint_as_float(rv[j].x & 0xffff0000u);
            ac[2] += wv * __uint_as_float(rv[j].y << 16);
            ac[3] += wv * __uint_as_float(rv[j].y & 0xffff0000u);
            ac[4] += wv * __uint_as_float(rv[j].z << 16);
            ac[5] += wv * __uint_as_float(rv[j].z & 0xffff0000u);
            ac[6] += wv * __uint_as_float(rv[j].w << 16);
            ac[7] += wv * __uint_as_float(rv[j].w & 0xffff0000u);
        }
    }
    bh8 o;
#pragma unroll
    for (int i = 0; i < 8; i++) o.v[i] = __float2bfloat16(ac[i]);
    *(bh8*)(tgt2 + (size_t)q * 256 + c0) = o;
}

// ---------------------------------------------------------------------------
extern "C" void kernel_launch(void* const* d_in, const int* in_sizes, int n_in,
                              void* d_out, int out_size, void* d_ws, size_t ws_size,
                              hipStream_t stream) {
    const float* tgt     = (const float*)d_in[0];
    const float* qpos    = (const float*)d_in[1];
    const float* refp    = (const float*)d_in[2];
    const float* src     = (const float*)d_in[3];
    const float* W_value = (const float*)d_in[6];
    const float* b_value = (const float*)d_in[7];
    const float* W_off   = (const float*)d_in[8];
    const float* b_off   = (const float*)d_in[9];
    const float* W_attn  = (const float*)d_in[10];
    const float* b_attn  = (const float*)d_in[11];
    const float* W_out   = (const float*)d_in[12];
    const float* b_out   = (const float*)d_in[13];
    const float* ln1_g   = (const float*)d_in[14];
    const float* ln1_b   = (const float*)d_in[15];
    const float* W1      = (const float*)d_in[16];
    const float* b1      = (const float*)d_in[17];
    const float* W2      = (const float*)d_in[18];
    const float* b2      = (const float*)d_in[19];
    const float* ln3_g   = (const float*)d_in[20];
    const float* ln3_b   = (const float*)d_in[21];
    float* out = (float*)d_out;

    // workspace layout
    char* p = (char*)d_ws;
    auto nxt = [&](size_t b) { char* r = p; p += (b + 255) & ~(size_t)255; return r; };
    __hip_bfloat16* Wvt    = (__hip_bfloat16*)nxt((size_t)256 * 256 * 2);
    __hip_bfloat16* Woat   = (__hip_bfloat16*)nxt((size_t)384 * 256 * 2);
    __hip_bfloat16* Woutt  = (__hip_bfloat16*)nxt((size_t)256 * 256 * 2);
    __hip_bfloat16* W1t    = (__hip_bfloat16*)nxt((size_t)1024 * 256 * 2);
    __hip_bfloat16* W2t    = (__hip_bfloat16*)nxt((size_t)256 * 1024 * 2);
    __hip_bfloat16* valueb = (__hip_bfloat16*)nxt((size_t)M_V * 256 * 2);  // dead after sampler
    float*          offb   = (float*)nxt((size_t)M_Q * 256 * 4);           // dead after sampler
    float*          attnb  = (float*)nxt((size_t)M_Q * 128 * 4);
    __hip_bfloat16* tgt2b  = (__hip_bfloat16*)nxt((size_t)M_Q * 256 * 2);
    __hip_bfloat16* t2ob   = (__hip_bfloat16*)nxt((size_t)M_Q * 256 * 2);
    float*          x      = (float*)nxt((size_t)M_Q * 256 * 4);
    __hip_bfloat16* xb     = (__hip_bfloat16*)nxt((size_t)M_Q * 256 * 2);
    __hip_bfloat16* hb     = (__hip_bfloat16*)nxt((size_t)M_Q * 1024 * 2);
    // FFN2 output (f32, 16.8 MB) overlays valueb (dead after sampler)
    float* f2o = (float*)valueb;

    dim3 blk(256);

    // 0) prep: weight transpose+cvt only
    prep_kernel<<<dim3(736), blk, 0, stream>>>(
        W_value, W_off, W_attn, W_out, W1, W2,
        Wvt, Woat, Woat + 256 * 256, Woutt, W1t, W2t);

    // 1) value GEMM ++ off/attn GEMM (64x128, fused cvt BK=64, XCD swizzle)
    mfma_gemm_vq<<<dim3(VT64 * 2 + 32 * 24), blk, 0, stream>>>(
        src, Wvt, b_value, valueb, tgt, qpos, Woat, b_off, b_attn, offb, attnb);

    // 2) deformable sampling -> tgt2 (bf16)
    sample_kernel<<<dim3(M_Q / QB), blk, 0, stream>>>(refp, offb, attnb, valueb, tgt2b);

    // 3) t2o = tgt2 @ W_out + b_out -> bf16  (COLS=2, 512 blocks)
    mfma_gemm64<256, 1, 2><<<dim3(M_Q / 64 * 2), blk, 0, stream>>>(
        tgt2b, Woutt, b_out, nullptr, t2ob, 256, 256, 256);

    // 4) x = LN1(tgt + t2o) -> f32 + bf16
    ln_kernel<true><<<dim3(M_Q / 4), blk, 0, stream>>>(
        nullptr, t2ob, nullptr, tgt, nullptr, ln1_g, ln1_b, x, xb);

    // 5) h = relu(x @ W1 + b1) -> bf16  (COLS=8, 2048 blocks)
    mfma_gemm64<256, 2, 8><<<dim3(M_Q / 64 * 8), blk, 0, stream>>>(
        xb, W1t, b1, nullptr, hb, 256, 256, 1024);

    // 6) f2o = h @ W2 + b2 -> f32, K=1024  (COLS=2, 512 blocks)
    mfma_gemm64<1024, 0, 2><<<dim3(M_Q / 64 * 2), blk, 0, stream>>>(
        hb, W2t, b2, f2o, nullptr, 1024, 1024, 256);

    // 7) out = LN3(x + f2o) -> f32
    ln_kernel<false><<<dim3(M_Q / 4), blk, 0, stream>>>(
        f2o, nullptr, nullptr, x, nullptr, ln3_g, ln3_b, out, nullptr);
}